// Round 9
// baseline (3897.086 us; speedup 1.0000x reference)
//
#include <hip/hip_runtime.h>
#include <math.h>

#define DMODEL 768
#define DEPTH 12
#define HEADS 12
#define HEADD 64
#define NTOK 197
#define BATCH 32
#define NPATCH 196
#define MTOK (BATCH * NTOK)    // 6304
#define MPAT (BATCH * NPATCH)  // 6272
#define QKVD 2304
#define MLPD 3072

typedef unsigned short u16;
typedef __attribute__((ext_vector_type(8))) short bf16x8;
typedef __attribute__((ext_vector_type(4))) float f32x4;

#define OFF_QKV 0
#define OFF_PROJ (QKVD * DMODEL)
#define OFF_FC1 (OFF_PROJ + DMODEL * DMODEL)
#define OFF_FC2 (OFF_FC1 + MLPD * DMODEL)
#define WTOTAL (OFF_FC2 + DMODEL * MLPD)   // 7077888 elements per layer

__device__ __forceinline__ u16 bf16r(float x) {
  union { float f; unsigned u; } c; c.f = x;
  unsigned u = c.u + 0x7FFF + ((c.u >> 16) & 1);
  return (u16)(u >> 16);
}
__device__ __forceinline__ float bf2f(u16 h) {
  union { unsigned u; float f; } c;
  c.u = (unsigned)h << 16;
  return c.f;
}
__device__ __forceinline__ float gelu_f(float x) {
  return 0.5f * x * (1.f + erff(x * 0.70710678118654752440f));
}
__device__ __forceinline__ void gload16(const void* g, void* l) {
  __builtin_amdgcn_global_load_lds(
      (const __attribute__((address_space(1))) void*)g,
      (__attribute__((address_space(3))) void*)l, 16, 0, 0);
}

// ---------------- block-wide reductions (256 threads) ----------------
__device__ __forceinline__ float blk_red_sum(float v, float* red) {
#pragma unroll
  for (int o = 32; o; o >>= 1) v += __shfl_xor(v, o);
  __syncthreads();
  if ((threadIdx.x & 63) == 0) red[threadIdx.x >> 6] = v;
  __syncthreads();
  return red[0] + red[1] + red[2] + red[3];
}
__device__ __forceinline__ float blk_red_max(float v, float* red) {
#pragma unroll
  for (int o = 32; o; o >>= 1) v = fmaxf(v, __shfl_xor(v, o));
  __syncthreads();
  if ((threadIdx.x & 63) == 0) red[threadIdx.x >> 6] = v;
  __syncthreads();
  return fmaxf(fmaxf(red[0], red[1]), fmaxf(red[2], red[3]));
}

// ---------------- f32 -> bf16 conversions ----------------
__global__ __launch_bounds__(256) void convert_bf16(const float* __restrict__ in,
                                                    u16* __restrict__ out, int n) {
  int i = (blockIdx.x * 256 + threadIdx.x) * 4;
  if (i >= n) return;
  float4 v = *(const float4*)(in + i);
  ushort4 o;
  o.x = bf16r(v.x); o.y = bf16r(v.y); o.z = bf16r(v.z); o.w = bf16r(v.w);
  *(ushort4*)(out + i) = o;
}

// one layer (fallback path)
__global__ __launch_bounds__(256) void convert_layer_w(
    const float* __restrict__ qkv_w, const float* __restrict__ proj_w,
    const float* __restrict__ fc1_w, const float* __restrict__ fc2_w,
    u16* __restrict__ wbuf) {
  int i = (blockIdx.x * 256 + threadIdx.x) * 4;
  if (i >= WTOTAL) return;
  const float* s;
  if (i < OFF_PROJ) s = qkv_w + i;
  else if (i < OFF_FC1) s = proj_w + (i - OFF_PROJ);
  else if (i < OFF_FC2) s = fc1_w + (i - OFF_FC1);
  else s = fc2_w + (i - OFF_FC2);
  float4 v = *(const float4*)s;
  ushort4 o;
  o.x = bf16r(v.x); o.y = bf16r(v.y); o.z = bf16r(v.z); o.w = bf16r(v.w);
  *(ushort4*)(wbuf + i) = o;
}

// all 12 layers in one dispatch. grid = (WTOTAL/1024, DEPTH)
__global__ __launch_bounds__(256) void convert_all_w(
    const float* __restrict__ qkv_w, const float* __restrict__ proj_w,
    const float* __restrict__ fc1_w, const float* __restrict__ fc2_w,
    u16* __restrict__ wall) {
  const int l = blockIdx.y;
  int i = (blockIdx.x * 256 + threadIdx.x) * 4;
  if (i >= WTOTAL) return;
  const float* s;
  if (i < OFF_PROJ) s = qkv_w + (size_t)l * QKVD * DMODEL + i;
  else if (i < OFF_FC1) s = proj_w + (size_t)l * DMODEL * DMODEL + (i - OFF_PROJ);
  else if (i < OFF_FC2) s = fc1_w + (size_t)l * MLPD * DMODEL + (i - OFF_FC1);
  else s = fc2_w + (size_t)l * DMODEL * MLPD + (i - OFF_FC2);
  float4 v = *(const float4*)s;
  ushort4 o;
  o.x = bf16r(v.x); o.y = bf16r(v.y); o.z = bf16r(v.z); o.w = bf16r(v.w);
  *(ushort4*)(wall + (size_t)l * WTOTAL + i) = o;
}

// ---------------- im2col (bf16 out) ----------------
__global__ __launch_bounds__(256) void im2col(const float* __restrict__ x,
                                              u16* __restrict__ col) {
  int idx = blockIdx.x * 256 + threadIdx.x;
  if (idx >= MPAT * DMODEL) return;
  int kk = idx % DMODEL;
  int m = idx / DMODEL;
  int bb = m / NPATCH, p = m % NPATCH;
  int ph = p / 14, pw = p % 14;
  int ch = kk >> 8, rem = kk & 255;
  int i = rem >> 4, j = rem & 15;
  col[idx] = bf16r(x[(((size_t)bb * 3 + ch) * 224 + ph * 16 + i) * 224 + pw * 16 + j]);
}

// ---------------- token assembly ----------------
__global__ __launch_bounds__(256) void assemble(const float* __restrict__ pat,
                                                const float* __restrict__ cls,
                                                const float* __restrict__ pos,
                                                float* __restrict__ tokens) {
  int idx = blockIdx.x * 256 + threadIdx.x;
  if (idx >= MTOK * DMODEL) return;
  int c = idx % DMODEL;
  int t = idx / DMODEL;
  int bb = t / NTOK, n = t % NTOK;
  float v;
  if (n == 0) v = cls[c];
  else v = pat[((size_t)bb * NPATCH + (n - 1)) * DMODEL + c];
  tokens[idx] = v + pos[n * DMODEL + c];
}

// ---------------- LayerNorm: one WAVE per token (4 tokens/block) ----------------
template <bool BF16OUT>
__global__ __launch_bounds__(256) void layernorm_w(const float* __restrict__ in,
                                                   const float* __restrict__ w,
                                                   const float* __restrict__ b,
                                                   void* __restrict__ outp,
                                                   int ntok) {
  const int wv = threadIdx.x >> 6, lane = threadIdx.x & 63;
  const int t = blockIdx.x * 4 + wv;
  if (t >= ntok) return;
  const f32x4* r = (const f32x4*)(in + (size_t)t * DMODEL);
  f32x4 x0 = r[lane], x1 = r[lane + 64], x2 = r[lane + 128];
  float s = (x0[0] + x0[1] + x0[2] + x0[3]) + (x1[0] + x1[1] + x1[2] + x1[3]) +
            (x2[0] + x2[1] + x2[2] + x2[3]);
#pragma unroll
  for (int o = 32; o; o >>= 1) s += __shfl_xor(s, o);
  const float mu = s * (1.f / 768.f);
  float vs = 0.f;
#pragma unroll
  for (int e = 0; e < 4; ++e) {
    float d0 = x0[e] - mu, d1 = x1[e] - mu, d2 = x2[e] - mu;
    vs += d0 * d0 + d1 * d1 + d2 * d2;
  }
#pragma unroll
  for (int o = 32; o; o >>= 1) vs += __shfl_xor(vs, o);
  const float is = rsqrtf(vs * (1.f / 768.f) + 1e-6f);
  const f32x4* wp = (const f32x4*)w;
  const f32x4* bp = (const f32x4*)b;
  f32x4 w0 = wp[lane], w1 = wp[lane + 64], w2 = wp[lane + 128];
  f32x4 b0 = bp[lane], b1 = bp[lane + 64], b2 = bp[lane + 128];
  f32x4 y0, y1, y2;
#pragma unroll
  for (int e = 0; e < 4; ++e) {
    y0[e] = (x0[e] - mu) * is * w0[e] + b0[e];
    y1[e] = (x1[e] - mu) * is * w1[e] + b1[e];
    y2[e] = (x2[e] - mu) * is * w2[e] + b2[e];
  }
  if (BF16OUT) {
    ushort4* o = (ushort4*)((u16*)outp + (size_t)t * DMODEL);
    ushort4 q0, q1, q2;
#pragma unroll
    for (int e = 0; e < 4; ++e) {
      ((u16*)&q0)[e] = bf16r(y0[e]);
      ((u16*)&q1)[e] = bf16r(y1[e]);
      ((u16*)&q2)[e] = bf16r(y2[e]);
    }
    o[lane] = q0; o[lane + 64] = q1; o[lane + 128] = q2;
  } else {
    f32x4* o = (f32x4*)((float*)outp + (size_t)t * DMODEL);
    o[lane] = y0; o[lane + 64] = y1; o[lane + 128] = y2;
  }
}

// ------- bf16 MFMA NT GEMM: 4-buffer, 3-ahead prefetch, counted vmcnt -------
// Loop order: ds_read -> STAGE(t+3) -> MFMA -> vmcnt(in-flight) -> barrier ->
// sched_barrier(0). Chunk swizzle key (row>>1)&3 both sides; n-fastest
// ordering within bijective XCD chunk.
// MODE 0: f32 = ; 1: f32 += ; 2: bf16 = gelu ; 3: bf16 =
template <int MODE, int TN>
__global__ __launch_bounds__(256) void gemm4(const u16* __restrict__ A,
                                             const u16* __restrict__ B,
                                             const float* __restrict__ bias,
                                             void* __restrict__ C,
                                             int M, int N, int K) {
  constexpr int NJ = TN / 32;
  constexpr int LPT = (TN == 128) ? 4 : 3;
  __shared__ u16 As[4][128 * 32];
  __shared__ u16 Bs[4][TN * 32];
  const int tid = threadIdx.x;
  const int w = tid >> 6, lane = tid & 63;

  const int nwg = gridDim.x * gridDim.y;
  int lin = blockIdx.y * gridDim.x + blockIdx.x;
  {
    int q = nwg >> 3, r = nwg & 7;
    int xcd = lin & 7, idx = lin >> 3;
    lin = (xcd < r ? xcd * (q + 1) : r * (q + 1) + (xcd - r) * q) + idx;
  }
  const int ntn = gridDim.y;
  const int m0 = (lin / ntn) * 128, n0 = (lin % ntn) * TN;

  const int wr = (w >> 1) * 64, wc = (w & 1) * (TN / 2);
  f32x4 acc[4][NJ] = {};

  const int srow = tid >> 2;
  const int scol = ((tid & 3) ^ ((srow >> 1) & 3)) * 8;
  int ar0 = m0 + srow;       if (ar0 >= M) ar0 = M - 1;
  int ar1 = m0 + 64 + srow;  if (ar1 >= M) ar1 = M - 1;
  const u16* Ag0 = A + (size_t)ar0 * K + scol;
  const u16* Ag1 = A + (size_t)ar1 * K + scol;
  const u16* Bg0 = B + (size_t)(n0 + srow) * K + scol;
  const u16* Bg1 = B + (size_t)(n0 + (TN == 128 ? 64 : 0) + srow) * K + scol;

  auto STAGE = [&](int buf, int kk) {
    gload16(Ag0 + kk, &As[buf][w * 512]);
    gload16(Ag1 + kk, &As[buf][2048 + w * 512]);
    gload16(Bg0 + kk, &Bs[buf][w * 512]);
    if (TN == 128) gload16(Bg1 + kk, &Bs[buf][2048 + w * 512]);
  };

  const int fr = lane & 15, lq = lane >> 4;
  const int kq = (lq ^ ((fr >> 1) & 3)) * 8;

  const int nt = K >> 5;  // >= 24 for all our shapes
  STAGE(0, 0);
  STAGE(1, 32);
  STAGE(2, 64);
  asm volatile("s_waitcnt vmcnt(%0)" ::"n"(2 * LPT) : "memory");
  __builtin_amdgcn_s_barrier();
  __builtin_amdgcn_sched_barrier(0);

  for (int t = 0; t < nt; ++t) {
    const int cur = t & 3;
    bf16x8 af[4], bfr[NJ];
#pragma unroll
    for (int i = 0; i < 4; ++i)
      af[i] = *(const bf16x8*)&As[cur][(wr + i * 16 + fr) * 32 + kq];
#pragma unroll
    for (int j = 0; j < NJ; ++j)
      bfr[j] = *(const bf16x8*)&Bs[cur][(wc + j * 16 + fr) * 32 + kq];
    if (t + 3 < nt) STAGE((t + 3) & 3, (t + 3) * 32);
#pragma unroll
    for (int i = 0; i < 4; ++i)
#pragma unroll
      for (int j = 0; j < NJ; ++j)
        acc[i][j] = __builtin_amdgcn_mfma_f32_16x16x32_bf16(af[i], bfr[j],
                                                            acc[i][j], 0, 0, 0);
    // tiles in flight beyond t+1 (t+1 must land before next step's ds_read)
    const int lim = (t + 3 < nt - 1) ? t + 3 : nt - 1;
    const int inflight = lim - t - 1;
    if (inflight >= 2)
      asm volatile("s_waitcnt vmcnt(%0)" ::"n"(2 * LPT) : "memory");
    else if (inflight == 1)
      asm volatile("s_waitcnt vmcnt(%0)" ::"n"(LPT) : "memory");
    else
      asm volatile("s_waitcnt vmcnt(0)" ::: "memory");
    __builtin_amdgcn_s_barrier();
    __builtin_amdgcn_sched_barrier(0);
  }

  const int fq = lq * 4;
#pragma unroll
  for (int j = 0; j < NJ; ++j) {
    const int n = n0 + wc + j * 16 + fr;
    const float bb = bias[n];
#pragma unroll
    for (int i = 0; i < 4; ++i) {
      const int mbase = m0 + wr + i * 16 + fq;
#pragma unroll
      for (int r = 0; r < 4; ++r) {
        const int m = mbase + r;
        if (m < M) {
          const float v = acc[i][j][r] + bb;
          if (MODE == 0) ((float*)C)[(size_t)m * N + n] = v;
          else if (MODE == 1) ((float*)C)[(size_t)m * N + n] += v;
          else if (MODE == 2) ((u16*)C)[(size_t)m * N + n] = bf16r(gelu_f(v));
          else ((u16*)C)[(size_t)m * N + n] = bf16r(v);
        }
      }
    }
  }
}

// ---------------- probe scores: one block per (b,h), bf16 qkv ----------------
__global__ __launch_bounds__(256) void probe_scores(const u16* __restrict__ qkv,
                                                    float* __restrict__ probs) {
  __shared__ float qrow[64];
  __shared__ float s[NTOK];
  __shared__ float red[4];
  const int bh = blockIdx.x;
  const int b = bh / HEADS, h = bh % HEADS;
  const int tid = threadIdx.x;
  const size_t row0 = (size_t)b * NTOK * QKVD;
  if (tid < 64) qrow[tid] = bf2f(qkv[row0 + h * HEADD + tid]);
  __syncthreads();
  const int sub = tid & 3;
  for (int k = tid >> 2; k < NTOK; k += 64) {
    const u16* kr = qkv + row0 + (size_t)k * QKVD + DMODEL + h * HEADD + sub * 16;
    bf16x8 k0 = *(const bf16x8*)kr;
    bf16x8 k1 = *(const bf16x8*)(kr + 8);
    float dot = 0.f;
#pragma unroll
    for (int e = 0; e < 8; ++e) {
      dot = fmaf(qrow[sub * 16 + e], bf2f((u16)k0[e]), dot);
      dot = fmaf(qrow[sub * 16 + 8 + e], bf2f((u16)k1[e]), dot);
    }
    dot += __shfl_xor(dot, 1);
    dot += __shfl_xor(dot, 2);
    if (sub == 0) s[k] = dot * 0.125f;
  }
  __syncthreads();
  float mx = -1e30f;
  for (int k = tid; k < NTOK; k += 256) mx = fmaxf(mx, s[k]);
  mx = blk_red_max(mx, red);
  float sm = 0.f;
  for (int k = tid; k < NTOK; k += 256) sm += expf(s[k] - mx);
  sm = blk_red_sum(sm, red);
  float inv = 1.f / sm;
  for (int k = tid; k < NTOK; k += 256)
    probs[(size_t)bh * NTOK + k] = expf(s[k] - mx) * inv;
}

// ---------------- top-k selection: one block per batch ----------------
__global__ __launch_bounds__(256) void topk_sel(const float* __restrict__ probs,
                                                const int* __restrict__ kpptr,
                                                int* __restrict__ topk) {
  __shared__ float accsc[NTOK];
  const int b = blockIdx.x, tid = threadIdx.x;
  for (int k = tid; k < NTOK; k += 256) {
    float a = 0.f;
#pragma unroll
    for (int h = 0; h < HEADS; ++h) a += probs[(size_t)(b * HEADS + h) * NTOK + k];
    accsc[k] = a;
  }
  __syncthreads();
  if (tid == 0) {
    int kpn = kpptr[0];
    if (kpn < 0) kpn = 0;
    if (kpn > 8) kpn = 8;
    for (int j = 0; j < kpn; ++j) {
      float best = -1e30f;
      int bi = 1;
      for (int k = 1; k < NTOK; ++k)
        if (accsc[k] > best) { best = accsc[k]; bi = k; }
      topk[b * 8 + j] = bi;
      accsc[bi] = -2e30f;
    }
    for (int j = kpn; j < 8; ++j) topk[b * 8 + j] = -1;
  }
}

// ---------------- MFMA attention, bf16 qkv input ----------------
__global__ __launch_bounds__(512, 1) void attn_mfma(
    const u16* __restrict__ qkv, const float* __restrict__ prompt_k,
    const float* __restrict__ prompt_v, const float* __restrict__ pk,
    const float* __restrict__ pv, const int* __restrict__ topk,
    const int* __restrict__ kpptr, u16* __restrict__ outp) {
  __shared__ u16 Ks[208 * 64];
  __shared__ u16 Vs[64 * 256];
  __shared__ u16 Ps[8][16 * 256];
  __shared__ float selb[NTOK];
  const int bh = blockIdx.x;
  const int b = bh / HEADS, h = bh % HEADS;
  const int tid = threadIdx.x, w = tid >> 6, lane = tid & 63;
  const int fr = lane & 15, lq = lane >> 4;

  int kpn = kpptr[0];
  if (kpn < 0) kpn = 0;
  if (kpn > 8) kpn = 8;
  for (int k = tid; k < NTOK; k += 512) {
    float sl = 0.f;
    for (int j = 0; j < kpn; ++j)
      if (topk[b * 8 + j] == k) sl = 1.f;
    selb[k] = sl;
  }
  __syncthreads();

  const size_t row0 = (size_t)b * NTOK * QKVD;
  const u16* kg = qkv + row0 + DMODEL + h * HEADD;
  const u16* vg = qkv + row0 + 2 * DMODEL + h * HEADD;
  for (int idx = tid; idx < 208 * 64; idx += 512) {
    int tok = idx >> 6, d = idx & 63;
    float v = 0.f;
    if (tok < NTOK) {
      v = bf2f(kg[(size_t)tok * QKVD + d]) + selb[tok] * pk[h * HEADD + d];
      if (tok == 0) v += prompt_k[h * HEADD + d];
    }
    int off = (tok * 128 + d * 2) ^ ((tok & 7) << 4);
    *(u16*)((char*)Ks + off) = bf16r(v);
  }
  for (int idx = tid; idx < 224 * 64; idx += 512) {
    int tok = idx >> 6, d = idx & 63;
    float v = 0.f;
    if (tok < NTOK) {
      v = bf2f(vg[(size_t)tok * QKVD + d]) + selb[tok] * pv[h * HEADD + d];
      if (tok == 0) v += prompt_v[h * HEADD + d];
    }
    int off = (d * 512 + tok * 2) ^ ((d & 7) << 4);
    *(u16*)((char*)Vs + off) = bf16r(v);
  }
  __syncthreads();

  u16* Pw = Ps[w];
  u16* ob = outp + (size_t)b * NTOK * DMODEL + h * HEADD;

#pragma unroll
  for (int pass = 0; pass < 2; ++pass) {
    const int qt = pass * 8 + w;
    const bool active = (qt < 14);
    if (active) {
      int qrow = qt * 16 + fr;
      if (qrow > NTOK - 1) qrow = NTOK - 1;
      const u16* qp = qkv + row0 + (size_t)qrow * QKVD + h * HEADD + lq * 8;
      bf16x8 aq0 = *(const bf16x8*)qp;
      bf16x8 aq1 = *(const bf16x8*)(qp + 32);
      f32x4 sa[13];
#pragma unroll
      for (int j = 0; j < 13; ++j) {
        int tok = j * 16 + fr;
        int o0 = (tok * 128 + lq * 16) ^ ((tok & 7) << 4);
        int o1 = (tok * 128 + 64 + lq * 16) ^ ((tok & 7) << 4);
        bf16x8 bk0 = *(const bf16x8*)((const char*)Ks + o0);
        bf16x8 bk1 = *(const bf16x8*)((const char*)Ks + o1);
        f32x4 z = {0.f, 0.f, 0.f, 0.f};
        z = __builtin_amdgcn_mfma_f32_16x16x32_bf16(aq0, bk0, z, 0, 0, 0);
        sa[j] = __builtin_amdgcn_mfma_f32_16x16x32_bf16(aq1, bk1, z, 0, 0, 0);
      }
      const bool v12 = (fr < 5);
      float m4[4] = {-1e30f, -1e30f, -1e30f, -1e30f};
#pragma unroll
      for (int j = 0; j < 13; ++j) {
        if (j == 12 && !v12) continue;
#pragma unroll
        for (int r = 0; r < 4; ++r) m4[r] = fmaxf(m4[r], sa[j][r] * 0.125f);
      }
#pragma unroll
      for (int o = 8; o; o >>= 1)
#pragma unroll
        for (int r = 0; r < 4; ++r) m4[r] = fmaxf(m4[r], __shfl_xor(m4[r], o));
      float s4[4] = {0.f, 0.f, 0.f, 0.f};
#pragma unroll
      for (int j = 0; j < 13; ++j) {
        const bool valid = (j < 12) || v12;
#pragma unroll
        for (int r = 0; r < 4; ++r) {
          float p = valid ? __expf(sa[j][r] * 0.125f - m4[r]) : 0.f;
          sa[j][r] = p;
          s4[r] += p;
        }
      }
#pragma unroll
      for (int o = 8; o; o >>= 1)
#pragma unroll
        for (int r = 0; r < 4; ++r) s4[r] += __shfl_xor(s4[r], o);
      float inv[4];
#pragma unroll
      for (int r = 0; r < 4; ++r) inv[r] = 1.f / s4[r];
#pragma unroll
      for (int r = 0; r < 4; ++r) {
        int row = lq * 4 + r;
        int rbase = row * 512, sw = (row & 7) << 4;
#pragma unroll
        for (int j = 0; j < 13; ++j) {
          int off = (rbase + (j * 16 + fr) * 2) ^ sw;
          *(u16*)((char*)Pw + off) = bf16r(sa[j][r] * inv[r]);
        }
        int offz = (rbase + (208 + fr) * 2) ^ sw;
        *(u16*)((char*)Pw + offz) = 0;
      }
    }
    __syncthreads();
    if (active) {
      f32x4 oa[4] = {};
#pragma unroll
      for (int kc = 0; kc < 7; ++kc) {
        int po = (fr * 512 + (kc * 32 + lq * 8) * 2) ^ ((fr & 7) << 4);
        bf16x8 pa = *(const bf16x8*)((const char*)Pw + po);
#pragma unroll
        for (int dt = 0; dt < 4; ++dt) {
          int d = dt * 16 + fr;
          int vo = (d * 512 + (kc * 32 + lq * 8) * 2) ^ ((d & 7) << 4);
          bf16x8 vb = *(const bf16x8*)((const char*)Vs + vo);
          oa[dt] = __builtin_amdgcn_mfma_f32_16x16x32_bf16(pa, vb, oa[dt], 0, 0, 0);
        }
      }
#pragma unroll
      for (int r = 0; r < 4; ++r) {
        int q = qt * 16 + lq * 4 + r;
        if (q < NTOK) {
          u16* orow = ob + (size_t)q * DMODEL;
#pragma unroll
          for (int dt = 0; dt < 4; ++dt) orow[dt * 16 + fr] = bf16r(oa[dt][r]);
        }
      }
    }
    __syncthreads();
  }
}

// ---------------- host ----------------
extern "C" void kernel_launch(void* const* d_in, const int* in_sizes, int n_in,
                              void* d_out, int out_size, void* d_ws, size_t ws_size,
                              hipStream_t stream) {
  const float* x = (const float*)d_in[0];
  const float* patch_w = (const float*)d_in[1];
  const float* patch_b = (const float*)d_in[2];
  const float* cls_tok = (const float*)d_in[3];
  const float* pos_emb = (const float*)d_in[4];
  const float* ln1_w = (const float*)d_in[5];
  const float* ln1_b = (const float*)d_in[6];
  const float* qkv_w = (const float*)d_in[7];
  const float* qkv_b = (const float*)d_in[8];
  const float* proj_w = (const float*)d_in[9];
  const float* proj_b = (const float*)d_in[10];
  const float* pk_par = (const float*)d_in[11];
  const float* pv_par = (const float*)d_in[12];
  const float* pr_k = (const float*)d_in[13];
  const float* pr_v = (const float*)d_in[14];
  const float* ln2_w = (const float*)d_in[15];
  const float* ln2_b = (const float*)d_in[16];
  const float* fc1_w = (const float*)d_in[17];
  const float* fc1_b = (const float*)d_in[18];
  const float* fc2_w = (const float*)d_in[19];
  const float* fc2_b = (const float*)d_in[20];
  const float* norm_w = (const float*)d_in[21];
  const float* norm_b = (const float*)d_in[22];
  const int* kp = (const int*)d_in[23];

  // workspace layout (bytes)
  char* base = (char*)d_ws;
  float* tokens = (float*)base;
  float* bufh = (float*)(base + 19365888ull);
  float* bufbig = (float*)(base + 38731776ull);
  u16* im2colb = (u16*)(base + 116195328ull);
  u16* patchwb = (u16*)(base + 125829120ull);
  int* topk = (int*)(base + 127008768ull);
  float* probs = (float*)(base + 127009792ull);
  u16* wbuf = (u16*)(base + 127312384ull);
  const size_t WBYTES = (size_t)WTOTAL * 2;
  const bool batch = ws_size >= 127312384ull + WBYTES * DEPTH;

  const int mt = (MTOK + 127) / 128;   // 50
  const int mtp = (MPAT + 127) / 128;  // 49
  const int lnb = (MTOK + 3) / 4;      // 1576

  if (batch)
    convert_all_w<<<dim3(WTOTAL / 1024, DEPTH), 256, 0, stream>>>(
        qkv_w, proj_w, fc1_w, fc2_w, wbuf);

  convert_bf16<<<(DMODEL * DMODEL / 4 + 255) / 256, 256, 0, stream>>>(
      patch_w, patchwb, DMODEL * DMODEL);
  im2col<<<(MPAT * DMODEL + 255) / 256, 256, 0, stream>>>(x, im2colb);
  gemm4<0, 64><<<dim3(mtp, DMODEL / 64), 256, 0, stream>>>(
      im2colb, patchwb, patch_b, bufh, MPAT, DMODEL, DMODEL);
  assemble<<<(MTOK * DMODEL + 255) / 256, 256, 0, stream>>>(bufh, cls_tok,
                                                            pos_emb, tokens);

  for (int l = 0; l < DEPTH; ++l) {
    u16* wl = batch ? (wbuf + (size_t)l * WTOTAL) : wbuf;
    if (!batch)
      convert_layer_w<<<(WTOTAL / 4 + 255) / 256, 256, 0, stream>>>(
          qkv_w + (size_t)l * QKVD * DMODEL,
          proj_w + (size_t)l * DMODEL * DMODEL,
          fc1_w + (size_t)l * MLPD * DMODEL,
          fc2_w + (size_t)l * DMODEL * MLPD, wl);
    layernorm_w<true><<<lnb, 256, 0, stream>>>(tokens, ln1_w + l * DMODEL,
                                               ln1_b + l * DMODEL, bufh, MTOK);
    gemm4<3, 128><<<dim3(mt, QKVD / 128), 256, 0, stream>>>(
        (const u16*)bufh, wl + OFF_QKV, qkv_b + l * QKVD, bufbig,
        MTOK, QKVD, DMODEL);
    probe_scores<<<BATCH * HEADS, 256, 0, stream>>>((const u16*)bufbig, probs);
    topk_sel<<<BATCH, 256, 0, stream>>>(probs, kp, topk);
    attn_mfma<<<BATCH * HEADS, 512, 0, stream>>>(
        (const u16*)bufbig, pr_k + l * HEADS * HEADD, pr_v + l * HEADS * HEADD,
        pk_par + l * HEADS * HEADD, pv_par + l * HEADS * HEADD, topk, kp,
        (u16*)bufh);
    gemm4<1, 64><<<dim3(mt, DMODEL / 64), 256, 0, stream>>>(
        (const u16*)bufh, wl + OFF_PROJ, proj_b + l * DMODEL, tokens,
        MTOK, DMODEL, DMODEL);
    layernorm_w<true><<<lnb, 256, 0, stream>>>(tokens, ln2_w + l * DMODEL,
                                               ln2_b + l * DMODEL, bufh, MTOK);
    gemm4<2, 128><<<dim3(mt, MLPD / 128), 256, 0, stream>>>(
        (const u16*)bufh, wl + OFF_FC1, fc1_b + l * MLPD, bufbig,
        MTOK, MLPD, DMODEL);
    gemm4<1, 64><<<dim3(mt, DMODEL / 64), 256, 0, stream>>>(
        (const u16*)bufbig, wl + OFF_FC2, fc2_b + l * DMODEL, tokens,
        MTOK, DMODEL, MLPD);
  }
  layernorm_w<false><<<lnb, 256, 0, stream>>>(tokens, norm_w, norm_b, d_out,
                                              MTOK);
}

// Round 11
// 3739.876 us; speedup vs baseline: 1.0420x; 1.0420x over previous
//
#include <hip/hip_runtime.h>
#include <math.h>

#define DMODEL 768
#define DEPTH 12
#define HEADS 12
#define HEADD 64
#define NTOK 197
#define BATCH 32
#define NPATCH 196
#define MTOK (BATCH * NTOK)    // 6304
#define MPAT (BATCH * NPATCH)  // 6272
#define QKVD 2304
#define MLPD 3072

typedef unsigned short u16;
typedef __attribute__((ext_vector_type(8))) short bf16x8;
typedef __attribute__((ext_vector_type(4))) float f32x4;

#define OFF_QKV 0
#define OFF_PROJ (QKVD * DMODEL)
#define OFF_FC1 (OFF_PROJ + DMODEL * DMODEL)
#define OFF_FC2 (OFF_FC1 + MLPD * DMODEL)
#define WTOTAL (OFF_FC2 + DMODEL * MLPD)   // 7077888 elements per layer

__device__ __forceinline__ u16 bf16r(float x) {
  union { float f; unsigned u; } c; c.f = x;
  unsigned u = c.u + 0x7FFF + ((c.u >> 16) & 1);
  return (u16)(u >> 16);
}
__device__ __forceinline__ float bf2f(u16 h) {
  union { unsigned u; float f; } c;
  c.u = (unsigned)h << 16;
  return c.f;
}
__device__ __forceinline__ float gelu_f(float x) {
  return 0.5f * x * (1.f + erff(x * 0.70710678118654752440f));
}
__device__ __forceinline__ void gload16(const void* g, void* l) {
  __builtin_amdgcn_global_load_lds(
      (const __attribute__((address_space(1))) void*)g,
      (__attribute__((address_space(3))) void*)l, 16, 0, 0);
}

// ---------------- block-wide reductions (256 threads) ----------------
__device__ __forceinline__ float blk_red_sum(float v, float* red) {
#pragma unroll
  for (int o = 32; o; o >>= 1) v += __shfl_xor(v, o);
  __syncthreads();
  if ((threadIdx.x & 63) == 0) red[threadIdx.x >> 6] = v;
  __syncthreads();
  return red[0] + red[1] + red[2] + red[3];
}
__device__ __forceinline__ float blk_red_max(float v, float* red) {
#pragma unroll
  for (int o = 32; o; o >>= 1) v = fmaxf(v, __shfl_xor(v, o));
  __syncthreads();
  if ((threadIdx.x & 63) == 0) red[threadIdx.x >> 6] = v;
  __syncthreads();
  return fmaxf(fmaxf(red[0], red[1]), fmaxf(red[2], red[3]));
}

// ---------------- f32 -> bf16 conversions ----------------
__global__ __launch_bounds__(256) void convert_bf16(const float* __restrict__ in,
                                                    u16* __restrict__ out, int n) {
  int i = (blockIdx.x * 256 + threadIdx.x) * 4;
  if (i >= n) return;
  float4 v = *(const float4*)(in + i);
  ushort4 o;
  o.x = bf16r(v.x); o.y = bf16r(v.y); o.z = bf16r(v.z); o.w = bf16r(v.w);
  *(ushort4*)(out + i) = o;
}

// one layer (fallback path)
__global__ __launch_bounds__(256) void convert_layer_w(
    const float* __restrict__ qkv_w, const float* __restrict__ proj_w,
    const float* __restrict__ fc1_w, const float* __restrict__ fc2_w,
    u16* __restrict__ wbuf) {
  int i = (blockIdx.x * 256 + threadIdx.x) * 4;
  if (i >= WTOTAL) return;
  const float* s;
  if (i < OFF_PROJ) s = qkv_w + i;
  else if (i < OFF_FC1) s = proj_w + (i - OFF_PROJ);
  else if (i < OFF_FC2) s = fc1_w + (i - OFF_FC1);
  else s = fc2_w + (i - OFF_FC2);
  float4 v = *(const float4*)s;
  ushort4 o;
  o.x = bf16r(v.x); o.y = bf16r(v.y); o.z = bf16r(v.z); o.w = bf16r(v.w);
  *(ushort4*)(wbuf + i) = o;
}

// all 12 layers in one dispatch. grid = (WTOTAL/1024, DEPTH)
__global__ __launch_bounds__(256) void convert_all_w(
    const float* __restrict__ qkv_w, const float* __restrict__ proj_w,
    const float* __restrict__ fc1_w, const float* __restrict__ fc2_w,
    u16* __restrict__ wall) {
  const int l = blockIdx.y;
  int i = (blockIdx.x * 256 + threadIdx.x) * 4;
  if (i >= WTOTAL) return;
  const float* s;
  if (i < OFF_PROJ) s = qkv_w + (size_t)l * QKVD * DMODEL + i;
  else if (i < OFF_FC1) s = proj_w + (size_t)l * DMODEL * DMODEL + (i - OFF_PROJ);
  else if (i < OFF_FC2) s = fc1_w + (size_t)l * MLPD * DMODEL + (i - OFF_FC1);
  else s = fc2_w + (size_t)l * DMODEL * MLPD + (i - OFF_FC2);
  float4 v = *(const float4*)s;
  ushort4 o;
  o.x = bf16r(v.x); o.y = bf16r(v.y); o.z = bf16r(v.z); o.w = bf16r(v.w);
  *(ushort4*)(wall + (size_t)l * WTOTAL + i) = o;
}

// ---------------- im2col (bf16 out) ----------------
__global__ __launch_bounds__(256) void im2col(const float* __restrict__ x,
                                              u16* __restrict__ col) {
  int idx = blockIdx.x * 256 + threadIdx.x;
  if (idx >= MPAT * DMODEL) return;
  int kk = idx % DMODEL;
  int m = idx / DMODEL;
  int bb = m / NPATCH, p = m % NPATCH;
  int ph = p / 14, pw = p % 14;
  int ch = kk >> 8, rem = kk & 255;
  int i = rem >> 4, j = rem & 15;
  col[idx] = bf16r(x[(((size_t)bb * 3 + ch) * 224 + ph * 16 + i) * 224 + pw * 16 + j]);
}

// ---------------- token assembly ----------------
__global__ __launch_bounds__(256) void assemble(const float* __restrict__ pat,
                                                const float* __restrict__ cls,
                                                const float* __restrict__ pos,
                                                float* __restrict__ tokens) {
  int idx = blockIdx.x * 256 + threadIdx.x;
  if (idx >= MTOK * DMODEL) return;
  int c = idx % DMODEL;
  int t = idx / DMODEL;
  int bb = t / NTOK, n = t % NTOK;
  float v;
  if (n == 0) v = cls[c];
  else v = pat[((size_t)bb * NPATCH + (n - 1)) * DMODEL + c];
  tokens[idx] = v + pos[n * DMODEL + c];
}

// ---------------- LayerNorm: one WAVE per token (4 tokens/block) ----------------
template <bool BF16OUT>
__global__ __launch_bounds__(256) void layernorm_w(const float* __restrict__ in,
                                                   const float* __restrict__ w,
                                                   const float* __restrict__ b,
                                                   void* __restrict__ outp,
                                                   int ntok) {
  const int wv = threadIdx.x >> 6, lane = threadIdx.x & 63;
  const int t = blockIdx.x * 4 + wv;
  if (t >= ntok) return;
  const f32x4* r = (const f32x4*)(in + (size_t)t * DMODEL);
  f32x4 x0 = r[lane], x1 = r[lane + 64], x2 = r[lane + 128];
  float s = (x0[0] + x0[1] + x0[2] + x0[3]) + (x1[0] + x1[1] + x1[2] + x1[3]) +
            (x2[0] + x2[1] + x2[2] + x2[3]);
#pragma unroll
  for (int o = 32; o; o >>= 1) s += __shfl_xor(s, o);
  const float mu = s * (1.f / 768.f);
  float vs = 0.f;
#pragma unroll
  for (int e = 0; e < 4; ++e) {
    float d0 = x0[e] - mu, d1 = x1[e] - mu, d2 = x2[e] - mu;
    vs += d0 * d0 + d1 * d1 + d2 * d2;
  }
#pragma unroll
  for (int o = 32; o; o >>= 1) vs += __shfl_xor(vs, o);
  const float is = rsqrtf(vs * (1.f / 768.f) + 1e-6f);
  const f32x4* wp = (const f32x4*)w;
  const f32x4* bp = (const f32x4*)b;
  f32x4 w0 = wp[lane], w1 = wp[lane + 64], w2 = wp[lane + 128];
  f32x4 b0 = bp[lane], b1 = bp[lane + 64], b2 = bp[lane + 128];
  f32x4 y0, y1, y2;
#pragma unroll
  for (int e = 0; e < 4; ++e) {
    y0[e] = (x0[e] - mu) * is * w0[e] + b0[e];
    y1[e] = (x1[e] - mu) * is * w1[e] + b1[e];
    y2[e] = (x2[e] - mu) * is * w2[e] + b2[e];
  }
  if (BF16OUT) {
    ushort4* o = (ushort4*)((u16*)outp + (size_t)t * DMODEL);
    ushort4 q0, q1, q2;
#pragma unroll
    for (int e = 0; e < 4; ++e) {
      ((u16*)&q0)[e] = bf16r(y0[e]);
      ((u16*)&q1)[e] = bf16r(y1[e]);
      ((u16*)&q2)[e] = bf16r(y2[e]);
    }
    o[lane] = q0; o[lane + 64] = q1; o[lane + 128] = q2;
  } else {
    f32x4* o = (f32x4*)((float*)outp + (size_t)t * DMODEL);
    o[lane] = y0; o[lane + 64] = y1; o[lane + 128] = y2;
  }
}

// ------- bf16 MFMA NT GEMM: 3-buffer, 2-ahead prefetch, counted vmcnt -------
// Round-8 structure. MODE 0: f32 = ; 1: f32 += ; 2: bf16 = gelu ; 3: bf16 =
template <int MODE, int TN>
__global__ __launch_bounds__(256) void gemm3(const u16* __restrict__ A,
                                             const u16* __restrict__ B,
                                             const float* __restrict__ bias,
                                             void* __restrict__ C,
                                             int M, int N, int K) {
  constexpr int NJ = TN / 32;
  constexpr int LPT = (TN == 128) ? 4 : 3;
  __shared__ u16 As[3][128 * 32];
  __shared__ u16 Bs[3][TN * 32];
  const int tid = threadIdx.x;
  const int w = tid >> 6, lane = tid & 63;

  const int nwg = gridDim.x * gridDim.y;
  int lin = blockIdx.y * gridDim.x + blockIdx.x;
  {
    int q = nwg >> 3, r = nwg & 7;
    int xcd = lin & 7, idx = lin >> 3;
    lin = (xcd < r ? xcd * (q + 1) : r * (q + 1) + (xcd - r) * q) + idx;
  }
  const int ntn = gridDim.y;
  const int m0 = (lin / ntn) * 128, n0 = (lin % ntn) * TN;

  const int wr = (w >> 1) * 64, wc = (w & 1) * (TN / 2);
  f32x4 acc[4][NJ] = {};

  const int srow = tid >> 2;
  const int scol = ((tid & 3) ^ ((srow >> 1) & 3)) * 8;
  int ar0 = m0 + srow;       if (ar0 >= M) ar0 = M - 1;
  int ar1 = m0 + 64 + srow;  if (ar1 >= M) ar1 = M - 1;
  const u16* Ag0 = A + (size_t)ar0 * K + scol;
  const u16* Ag1 = A + (size_t)ar1 * K + scol;
  const u16* Bg0 = B + (size_t)(n0 + srow) * K + scol;
  const u16* Bg1 = B + (size_t)(n0 + (TN == 128 ? 64 : 0) + srow) * K + scol;

  auto STAGE = [&](int buf, int kk) {
    gload16(Ag0 + kk, &As[buf][w * 512]);
    gload16(Ag1 + kk, &As[buf][2048 + w * 512]);
    gload16(Bg0 + kk, &Bs[buf][w * 512]);
    if (TN == 128) gload16(Bg1 + kk, &Bs[buf][2048 + w * 512]);
  };

  const int fr = lane & 15, lq = lane >> 4;
  const int kq = (lq ^ ((fr >> 1) & 3)) * 8;

  const int nt = K >> 5;
  STAGE(0, 0);
  STAGE(1, 32);
  asm volatile("s_waitcnt vmcnt(%0)" ::"n"(LPT) : "memory");
  __builtin_amdgcn_s_barrier();
  __builtin_amdgcn_sched_barrier(0);

  for (int t = 0; t < nt; ++t) {
    const int cur = t % 3;
    bf16x8 af[4], bfr[NJ];
#pragma unroll
    for (int i = 0; i < 4; ++i)
      af[i] = *(const bf16x8*)&As[cur][(wr + i * 16 + fr) * 32 + kq];
#pragma unroll
    for (int j = 0; j < NJ; ++j)
      bfr[j] = *(const bf16x8*)&Bs[cur][(wc + j * 16 + fr) * 32 + kq];
    const bool more = (t + 2 < nt);
    if (more) STAGE((t + 2) % 3, (t + 2) * 32);
#pragma unroll
    for (int i = 0; i < 4; ++i)
#pragma unroll
      for (int j = 0; j < NJ; ++j)
        acc[i][j] = __builtin_amdgcn_mfma_f32_16x16x32_bf16(af[i], bfr[j],
                                                            acc[i][j], 0, 0, 0);
    if (more)
      asm volatile("s_waitcnt vmcnt(%0)" ::"n"(LPT) : "memory");
    else
      asm volatile("s_waitcnt vmcnt(0)" ::: "memory");
    __builtin_amdgcn_s_barrier();
    __builtin_amdgcn_sched_barrier(0);
  }

  const int fq = lq * 4;
#pragma unroll
  for (int j = 0; j < NJ; ++j) {
    const int n = n0 + wc + j * 16 + fr;
    const float bb = bias[n];
#pragma unroll
    for (int i = 0; i < 4; ++i) {
      const int mbase = m0 + wr + i * 16 + fq;
#pragma unroll
      for (int r = 0; r < 4; ++r) {
        const int m = mbase + r;
        if (m < M) {
          const float v = acc[i][j][r] + bb;
          if (MODE == 0) ((float*)C)[(size_t)m * N + n] = v;
          else if (MODE == 1) ((float*)C)[(size_t)m * N + n] += v;
          else if (MODE == 2) ((u16*)C)[(size_t)m * N + n] = bf16r(gelu_f(v));
          else ((u16*)C)[(size_t)m * N + n] = bf16r(v);
        }
      }
    }
  }
}

// ---------------- probe scores: one block per (b,h), bf16 qkv ----------------
__global__ __launch_bounds__(256) void probe_scores(const u16* __restrict__ qkv,
                                                    float* __restrict__ probs) {
  __shared__ float qrow[64];
  __shared__ float s[NTOK];
  __shared__ float red[4];
  const int bh = blockIdx.x;
  const int b = bh / HEADS, h = bh % HEADS;
  const int tid = threadIdx.x;
  const size_t row0 = (size_t)b * NTOK * QKVD;
  if (tid < 64) qrow[tid] = bf2f(qkv[row0 + h * HEADD + tid]);
  __syncthreads();
  const int sub = tid & 3;
  for (int k = tid >> 2; k < NTOK; k += 64) {
    const u16* kr = qkv + row0 + (size_t)k * QKVD + DMODEL + h * HEADD + sub * 16;
    bf16x8 k0 = *(const bf16x8*)kr;
    bf16x8 k1 = *(const bf16x8*)(kr + 8);
    float dot = 0.f;
#pragma unroll
    for (int e = 0; e < 8; ++e) {
      dot = fmaf(qrow[sub * 16 + e], bf2f((u16)k0[e]), dot);
      dot = fmaf(qrow[sub * 16 + 8 + e], bf2f((u16)k1[e]), dot);
    }
    dot += __shfl_xor(dot, 1);
    dot += __shfl_xor(dot, 2);
    if (sub == 0) s[k] = dot * 0.125f;
  }
  __syncthreads();
  float mx = -1e30f;
  for (int k = tid; k < NTOK; k += 256) mx = fmaxf(mx, s[k]);
  mx = blk_red_max(mx, red);
  float sm = 0.f;
  for (int k = tid; k < NTOK; k += 256) sm += expf(s[k] - mx);
  sm = blk_red_sum(sm, red);
  float inv = 1.f / sm;
  for (int k = tid; k < NTOK; k += 256)
    probs[(size_t)bh * NTOK + k] = expf(s[k] - mx) * inv;
}

// ---------------- top-k selection: one block per batch ----------------
__global__ __launch_bounds__(256) void topk_sel(const float* __restrict__ probs,
                                                const int* __restrict__ kpptr,
                                                int* __restrict__ topk) {
  __shared__ float accsc[NTOK];
  const int b = blockIdx.x, tid = threadIdx.x;
  for (int k = tid; k < NTOK; k += 256) {
    float a = 0.f;
#pragma unroll
    for (int h = 0; h < HEADS; ++h) a += probs[(size_t)(b * HEADS + h) * NTOK + k];
    accsc[k] = a;
  }
  __syncthreads();
  if (tid == 0) {
    int kpn = kpptr[0];
    if (kpn < 0) kpn = 0;
    if (kpn > 8) kpn = 8;
    for (int j = 0; j < kpn; ++j) {
      float best = -1e30f;
      int bi = 1;
      for (int k = 1; k < NTOK; ++k)
        if (accsc[k] > best) { best = accsc[k]; bi = k; }
      topk[b * 8 + j] = bi;
      accsc[bi] = -2e30f;
    }
    for (int j = kpn; j < 8; ++j) topk[b * 8 + j] = -1;
  }
}

// ---------------- MFMA attention, bf16 qkv input ----------------
__global__ __launch_bounds__(512, 1) void attn_mfma(
    const u16* __restrict__ qkv, const float* __restrict__ prompt_k,
    const float* __restrict__ prompt_v, const float* __restrict__ pk,
    const float* __restrict__ pv, const int* __restrict__ topk,
    const int* __restrict__ kpptr, u16* __restrict__ outp) {
  __shared__ u16 Ks[208 * 64];
  __shared__ u16 Vs[64 * 256];
  __shared__ u16 Ps[8][16 * 256];
  __shared__ float selb[NTOK];
  const int bh = blockIdx.x;
  const int b = bh / HEADS, h = bh % HEADS;
  const int tid = threadIdx.x, w = tid >> 6, lane = tid & 63;
  const int fr = lane & 15, lq = lane >> 4;

  int kpn = kpptr[0];
  if (kpn < 0) kpn = 0;
  if (kpn > 8) kpn = 8;
  for (int k = tid; k < NTOK; k += 512) {
    float sl = 0.f;
    for (int j = 0; j < kpn; ++j)
      if (topk[b * 8 + j] == k) sl = 1.f;
    selb[k] = sl;
  }
  __syncthreads();

  const size_t row0 = (size_t)b * NTOK * QKVD;
  const u16* kg = qkv + row0 + DMODEL + h * HEADD;
  const u16* vg = qkv + row0 + 2 * DMODEL + h * HEADD;
  for (int idx = tid; idx < 208 * 64; idx += 512) {
    int tok = idx >> 6, d = idx & 63;
    float v = 0.f;
    if (tok < NTOK) {
      v = bf2f(kg[(size_t)tok * QKVD + d]) + selb[tok] * pk[h * HEADD + d];
      if (tok == 0) v += prompt_k[h * HEADD + d];
    }
    int off = (tok * 128 + d * 2) ^ ((tok & 7) << 4);
    *(u16*)((char*)Ks + off) = bf16r(v);
  }
  for (int idx = tid; idx < 224 * 64; idx += 512) {
    int tok = idx >> 6, d = idx & 63;
    float v = 0.f;
    if (tok < NTOK) {
      v = bf2f(vg[(size_t)tok * QKVD + d]) + selb[tok] * pv[h * HEADD + d];
      if (tok == 0) v += prompt_v[h * HEADD + d];
    }
    int off = (d * 512 + tok * 2) ^ ((d & 7) << 4);
    *(u16*)((char*)Vs + off) = bf16r(v);
  }
  __syncthreads();

  u16* Pw = Ps[w];
  u16* ob = outp + (size_t)b * NTOK * DMODEL + h * HEADD;

#pragma unroll
  for (int pass = 0; pass < 2; ++pass) {
    const int qt = pass * 8 + w;
    const bool active = (qt < 14);
    if (active) {
      int qrow = qt * 16 + fr;
      if (qrow > NTOK - 1) qrow = NTOK - 1;
      const u16* qp = qkv + row0 + (size_t)qrow * QKVD + h * HEADD + lq * 8;
      bf16x8 aq0 = *(const bf16x8*)qp;
      bf16x8 aq1 = *(const bf16x8*)(qp + 32);
      f32x4 sa[13];
#pragma unroll
      for (int j = 0; j < 13; ++j) {
        int tok = j * 16 + fr;
        int o0 = (tok * 128 + lq * 16) ^ ((tok & 7) << 4);
        int o1 = (tok * 128 + 64 + lq * 16) ^ ((tok & 7) << 4);
        bf16x8 bk0 = *(const bf16x8*)((const char*)Ks + o0);
        bf16x8 bk1 = *(const bf16x8*)((const char*)Ks + o1);
        f32x4 z = {0.f, 0.f, 0.f, 0.f};
        z = __builtin_amdgcn_mfma_f32_16x16x32_bf16(aq0, bk0, z, 0, 0, 0);
        sa[j] = __builtin_amdgcn_mfma_f32_16x16x32_bf16(aq1, bk1, z, 0, 0, 0);
      }
      const bool v12 = (fr < 5);
      float m4[4] = {-1e30f, -1e30f, -1e30f, -1e30f};
#pragma unroll
      for (int j = 0; j < 13; ++j) {
        if (j == 12 && !v12) continue;
#pragma unroll
        for (int r = 0; r < 4; ++r) m4[r] = fmaxf(m4[r], sa[j][r] * 0.125f);
      }
#pragma unroll
      for (int o = 8; o; o >>= 1)
#pragma unroll
        for (int r = 0; r < 4; ++r) m4[r] = fmaxf(m4[r], __shfl_xor(m4[r], o));
      float s4[4] = {0.f, 0.f, 0.f, 0.f};
#pragma unroll
      for (int j = 0; j < 13; ++j) {
        const bool valid = (j < 12) || v12;
#pragma unroll
        for (int r = 0; r < 4; ++r) {
          float p = valid ? __expf(sa[j][r] * 0.125f - m4[r]) : 0.f;
          sa[j][r] = p;
          s4[r] += p;
        }
      }
#pragma unroll
      for (int o = 8; o; o >>= 1)
#pragma unroll
        for (int r = 0; r < 4; ++r) s4[r] += __shfl_xor(s4[r], o);
      float inv[4];
#pragma unroll
      for (int r = 0; r < 4; ++r) inv[r] = 1.f / s4[r];
#pragma unroll
      for (int r = 0; r < 4; ++r) {
        int row = lq * 4 + r;
        int rbase = row * 512, sw = (row & 7) << 4;
#pragma unroll
        for (int j = 0; j < 13; ++j) {
          int off = (rbase + (j * 16 + fr) * 2) ^ sw;
          *(u16*)((char*)Pw + off) = bf16r(sa[j][r] * inv[r]);
        }
        int offz = (rbase + (208 + fr) * 2) ^ sw;
        *(u16*)((char*)Pw + offz) = 0;
      }
    }
    __syncthreads();
    if (active) {
      f32x4 oa[4] = {};
#pragma unroll
      for (int kc = 0; kc < 7; ++kc) {
        int po = (fr * 512 + (kc * 32 + lq * 8) * 2) ^ ((fr & 7) << 4);
        bf16x8 pa = *(const bf16x8*)((const char*)Pw + po);
#pragma unroll
        for (int dt = 0; dt < 4; ++dt) {
          int d = dt * 16 + fr;
          int vo = (d * 512 + (kc * 32 + lq * 8) * 2) ^ ((d & 7) << 4);
          bf16x8 vb = *(const bf16x8*)((const char*)Vs + vo);
          oa[dt] = __builtin_amdgcn_mfma_f32_16x16x32_bf16(pa, vb, oa[dt], 0, 0, 0);
        }
      }
#pragma unroll
      for (int r = 0; r < 4; ++r) {
        int q = qt * 16 + lq * 4 + r;
        if (q < NTOK) {
          u16* orow = ob + (size_t)q * DMODEL;
#pragma unroll
          for (int dt = 0; dt < 4; ++dt) orow[dt * 16 + fr] = bf16r(oa[dt][r]);
        }
      }
    }
    __syncthreads();
  }
}

// ---------------- host ----------------
extern "C" void kernel_launch(void* const* d_in, const int* in_sizes, int n_in,
                              void* d_out, int out_size, void* d_ws, size_t ws_size,
                              hipStream_t stream) {
  const float* x = (const float*)d_in[0];
  const float* patch_w = (const float*)d_in[1];
  const float* patch_b = (const float*)d_in[2];
  const float* cls_tok = (const float*)d_in[3];
  const float* pos_emb = (const float*)d_in[4];
  const float* ln1_w = (const float*)d_in[5];
  const float* ln1_b = (const float*)d_in[6];
  const float* qkv_w = (const float*)d_in[7];
  const float* qkv_b = (const float*)d_in[8];
  const float* proj_w = (const float*)d_in[9];
  const float* proj_b = (const float*)d_in[10];
  const float* pk_par = (const float*)d_in[11];
  const float* pv_par = (const float*)d_in[12];
  const float* pr_k = (const float*)d_in[13];
  const float* pr_v = (const float*)d_in[14];
  const float* ln2_w = (const float*)d_in[15];
  const float* ln2_b = (const float*)d_in[16];
  const float* fc1_w = (const float*)d_in[17];
  const float* fc1_b = (const float*)d_in[18];
  const float* fc2_w = (const float*)d_in[19];
  const float* fc2_b = (const float*)d_in[20];
  const float* norm_w = (const float*)d_in[21];
  const float* norm_b = (const float*)d_in[22];
  const int* kp = (const int*)d_in[23];

  // workspace layout (bytes)
  char* base = (char*)d_ws;
  float* tokens = (float*)base;
  float* bufh = (float*)(base + 19365888ull);
  float* bufbig = (float*)(base + 38731776ull);
  u16* im2colb = (u16*)(base + 116195328ull);
  u16* patchwb = (u16*)(base + 125829120ull);
  int* topk = (int*)(base + 127008768ull);
  float* probs = (float*)(base + 127009792ull);
  u16* wbuf = (u16*)(base + 127312384ull);
  const size_t WBYTES = (size_t)WTOTAL * 2;
  const bool batch = ws_size >= 127312384ull + WBYTES * DEPTH;

  const int mt = (MTOK + 127) / 128;   // 50
  const int mtp = (MPAT + 127) / 128;  // 49
  const int lnb = (MTOK + 3) / 4;      // 1576

  if (batch)
    convert_all_w<<<dim3(WTOTAL / 1024, DEPTH), 256, 0, stream>>>(
        qkv_w, proj_w, fc1_w, fc2_w, wbuf);

  convert_bf16<<<(DMODEL * DMODEL / 4 + 255) / 256, 256, 0, stream>>>(
      patch_w, patchwb, DMODEL * DMODEL);
  im2col<<<(MPAT * DMODEL + 255) / 256, 256, 0, stream>>>(x, im2colb);
  gemm3<0, 64><<<dim3(mtp, DMODEL / 64), 256, 0, stream>>>(
      im2colb, patchwb, patch_b, bufh, MPAT, DMODEL, DMODEL);
  assemble<<<(MTOK * DMODEL + 255) / 256, 256, 0, stream>>>(bufh, cls_tok,
                                                            pos_emb, tokens);

  for (int l = 0; l < DEPTH; ++l) {
    u16* wl = batch ? (wbuf + (size_t)l * WTOTAL) : wbuf;
    if (!batch)
      convert_layer_w<<<(WTOTAL / 4 + 255) / 256, 256, 0, stream>>>(
          qkv_w + (size_t)l * QKVD * DMODEL,
          proj_w + (size_t)l * DMODEL * DMODEL,
          fc1_w + (size_t)l * MLPD * DMODEL,
          fc2_w + (size_t)l * DMODEL * MLPD, wl);
    layernorm_w<true><<<lnb, 256, 0, stream>>>(tokens, ln1_w + l * DMODEL,
                                               ln1_b + l * DMODEL, bufh, MTOK);
    gemm3<3, 128><<<dim3(mt, QKVD / 128), 256, 0, stream>>>(
        (const u16*)bufh, wl + OFF_QKV, qkv_b + l * QKVD, bufbig,
        MTOK, QKVD, DMODEL);
    probe_scores<<<BATCH * HEADS, 256, 0, stream>>>((const u16*)bufbig, probs);
    topk_sel<<<BATCH, 256, 0, stream>>>(probs, kp, topk);
    attn_mfma<<<BATCH * HEADS, 512, 0, stream>>>(
        (const u16*)bufbig, pr_k + l * HEADS * HEADD, pr_v + l * HEADS * HEADD,
        pk_par + l * HEADS * HEADD, pv_par + l * HEADS * HEADD, topk, kp,
        (u16*)bufh);
    gemm3<1, 64><<<dim3(mt, DMODEL / 64), 256, 0, stream>>>(
        (const u16*)bufh, wl + OFF_PROJ, proj_b + l * DMODEL, tokens,
        MTOK, DMODEL, DMODEL);
    layernorm_w<true><<<lnb, 256, 0, stream>>>(tokens, ln2_w + l * DMODEL,
                                               ln2_b + l * DMODEL, bufh, MTOK);
    gemm3<2, 128><<<dim3(mt, MLPD / 128), 256, 0, stream>>>(
        (const u16*)bufh, wl + OFF_FC1, fc1_b + l * MLPD, bufbig,
        MTOK, MLPD, DMODEL);
    gemm3<1, 64><<<dim3(mt, DMODEL / 64), 256, 0, stream>>>(
        (const u16*)bufbig, wl + OFF_FC2, fc2_b + l * DMODEL, tokens,
        MTOK, DMODEL, MLPD);
  }
  layernorm_w<false><<<lnb, 256, 0, stream>>>(tokens, norm_w, norm_b, d_out,
                                              MTOK);
}

// Round 14
// 3487.043 us; speedup vs baseline: 1.1176x; 1.0725x over previous
//
#include <hip/hip_runtime.h>
#include <math.h>

#define DMODEL 768
#define DEPTH 12
#define HEADS 12
#define HEADD 64
#define NTOK 197
#define BATCH 32
#define NPATCH 196
#define MTOK (BATCH * NTOK)    // 6304
#define MPAT (BATCH * NPATCH)  // 6272
#define QKVD 2304
#define MLPD 3072

typedef unsigned short u16;
typedef __attribute__((ext_vector_type(8))) short bf16x8;
typedef __attribute__((ext_vector_type(4))) float f32x4;

#define OFF_QKV 0
#define OFF_PROJ (QKVD * DMODEL)
#define OFF_FC1 (OFF_PROJ + DMODEL * DMODEL)
#define OFF_FC2 (OFF_FC1 + MLPD * DMODEL)
#define WTOTAL (OFF_FC2 + DMODEL * MLPD)   // 7077888 elements per layer

__device__ __forceinline__ u16 bf16r(float x) {
  union { float f; unsigned u; } c; c.f = x;
  unsigned u = c.u + 0x7FFF + ((c.u >> 16) & 1);
  return (u16)(u >> 16);
}
__device__ __forceinline__ float bf2f(u16 h) {
  union { unsigned u; float f; } c;
  c.u = (unsigned)h << 16;
  return c.f;
}
__device__ __forceinline__ float gelu_f(float x) {
  return 0.5f * x * (1.f + erff(x * 0.70710678118654752440f));
}
__device__ __forceinline__ void gload16(const void* g, void* l) {
  __builtin_amdgcn_global_load_lds(
      (const __attribute__((address_space(1))) void*)g,
      (__attribute__((address_space(3))) void*)l, 16, 0, 0);
}

// ---------------- block-wide reductions (256 threads) ----------------
__device__ __forceinline__ float blk_red_sum(float v, float* red) {
#pragma unroll
  for (int o = 32; o; o >>= 1) v += __shfl_xor(v, o);
  __syncthreads();
  if ((threadIdx.x & 63) == 0) red[threadIdx.x >> 6] = v;
  __syncthreads();
  return red[0] + red[1] + red[2] + red[3];
}
__device__ __forceinline__ float blk_red_max(float v, float* red) {
#pragma unroll
  for (int o = 32; o; o >>= 1) v = fmaxf(v, __shfl_xor(v, o));
  __syncthreads();
  if ((threadIdx.x & 63) == 0) red[threadIdx.x >> 6] = v;
  __syncthreads();
  return fmaxf(fmaxf(red[0], red[1]), fmaxf(red[2], red[3]));
}

// ---------------- f32 -> bf16 conversions ----------------
__global__ __launch_bounds__(256) void convert_bf16(const float* __restrict__ in,
                                                    u16* __restrict__ out, int n) {
  int i = (blockIdx.x * 256 + threadIdx.x) * 4;
  if (i >= n) return;
  float4 v = *(const float4*)(in + i);
  ushort4 o;
  o.x = bf16r(v.x); o.y = bf16r(v.y); o.z = bf16r(v.z); o.w = bf16r(v.w);
  *(ushort4*)(out + i) = o;
}

// one layer (fallback path)
__global__ __launch_bounds__(256) void convert_layer_w(
    const float* __restrict__ qkv_w, const float* __restrict__ proj_w,
    const float* __restrict__ fc1_w, const float* __restrict__ fc2_w,
    u16* __restrict__ wbuf) {
  int i = (blockIdx.x * 256 + threadIdx.x) * 4;
  if (i >= WTOTAL) return;
  const float* s;
  if (i < OFF_PROJ) s = qkv_w + i;
  else if (i < OFF_FC1) s = proj_w + (i - OFF_PROJ);
  else if (i < OFF_FC2) s = fc1_w + (i - OFF_FC1);
  else s = fc2_w + (i - OFF_FC2);
  float4 v = *(const float4*)s;
  ushort4 o;
  o.x = bf16r(v.x); o.y = bf16r(v.y); o.z = bf16r(v.z); o.w = bf16r(v.w);
  *(ushort4*)(wbuf + i) = o;
}

// all 12 layers in one dispatch. grid = (WTOTAL/1024, DEPTH)
__global__ __launch_bounds__(256) void convert_all_w(
    const float* __restrict__ qkv_w, const float* __restrict__ proj_w,
    const float* __restrict__ fc1_w, const float* __restrict__ fc2_w,
    u16* __restrict__ wall) {
  const int l = blockIdx.y;
  int i = (blockIdx.x * 256 + threadIdx.x) * 4;
  if (i >= WTOTAL) return;
  const float* s;
  if (i < OFF_PROJ) s = qkv_w + (size_t)l * QKVD * DMODEL + i;
  else if (i < OFF_FC1) s = proj_w + (size_t)l * DMODEL * DMODEL + (i - OFF_PROJ);
  else if (i < OFF_FC2) s = fc1_w + (size_t)l * MLPD * DMODEL + (i - OFF_FC1);
  else s = fc2_w + (size_t)l * DMODEL * MLPD + (i - OFF_FC2);
  float4 v = *(const float4*)s;
  ushort4 o;
  o.x = bf16r(v.x); o.y = bf16r(v.y); o.z = bf16r(v.z); o.w = bf16r(v.w);
  *(ushort4*)(wall + (size_t)l * WTOTAL + i) = o;
}

// ---------------- im2col (bf16 out) ----------------
__global__ __launch_bounds__(256) void im2col(const float* __restrict__ x,
                                              u16* __restrict__ col) {
  int idx = blockIdx.x * 256 + threadIdx.x;
  if (idx >= MPAT * DMODEL) return;
  int kk = idx % DMODEL;
  int m = idx / DMODEL;
  int bb = m / NPATCH, p = m % NPATCH;
  int ph = p / 14, pw = p % 14;
  int ch = kk >> 8, rem = kk & 255;
  int i = rem >> 4, j = rem & 15;
  col[idx] = bf16r(x[(((size_t)bb * 3 + ch) * 224 + ph * 16 + i) * 224 + pw * 16 + j]);
}

// ---------------- token assembly ----------------
__global__ __launch_bounds__(256) void assemble(const float* __restrict__ pat,
                                                const float* __restrict__ cls,
                                                const float* __restrict__ pos,
                                                float* __restrict__ tokens) {
  int idx = blockIdx.x * 256 + threadIdx.x;
  if (idx >= MTOK * DMODEL) return;
  int c = idx % DMODEL;
  int t = idx / DMODEL;
  int bb = t / NTOK, n = t % NTOK;
  float v;
  if (n == 0) v = cls[c];
  else v = pat[((size_t)bb * NPATCH + (n - 1)) * DMODEL + c];
  tokens[idx] = v + pos[n * DMODEL + c];
}

// ---------------- LayerNorm: one WAVE per token (4 tokens/block) ----------------
template <bool BF16OUT>
__global__ __launch_bounds__(256) void layernorm_w(const float* __restrict__ in,
                                                   const float* __restrict__ w,
                                                   const float* __restrict__ b,
                                                   void* __restrict__ outp,
                                                   int ntok) {
  const int wv = threadIdx.x >> 6, lane = threadIdx.x & 63;
  const int t = blockIdx.x * 4 + wv;
  if (t >= ntok) return;
  const f32x4* r = (const f32x4*)(in + (size_t)t * DMODEL);
  f32x4 x0 = r[lane], x1 = r[lane + 64], x2 = r[lane + 128];
  float s = (x0[0] + x0[1] + x0[2] + x0[3]) + (x1[0] + x1[1] + x1[2] + x1[3]) +
            (x2[0] + x2[1] + x2[2] + x2[3]);
#pragma unroll
  for (int o = 32; o; o >>= 1) s += __shfl_xor(s, o);
  const float mu = s * (1.f / 768.f);
  float vs = 0.f;
#pragma unroll
  for (int e = 0; e < 4; ++e) {
    float d0 = x0[e] - mu, d1 = x1[e] - mu, d2 = x2[e] - mu;
    vs += d0 * d0 + d1 * d1 + d2 * d2;
  }
#pragma unroll
  for (int o = 32; o; o >>= 1) vs += __shfl_xor(vs, o);
  const float is = rsqrtf(vs * (1.f / 768.f) + 1e-6f);
  const f32x4* wp = (const f32x4*)w;
  const f32x4* bp = (const f32x4*)b;
  f32x4 w0 = wp[lane], w1 = wp[lane + 64], w2 = wp[lane + 128];
  f32x4 b0 = bp[lane], b1 = bp[lane + 64], b2 = bp[lane + 128];
  f32x4 y0, y1, y2;
#pragma unroll
  for (int e = 0; e < 4; ++e) {
    y0[e] = (x0[e] - mu) * is * w0[e] + b0[e];
    y1[e] = (x1[e] - mu) * is * w1[e] + b1[e];
    y2[e] = (x2[e] - mu) * is * w2[e] + b2[e];
  }
  if (BF16OUT) {
    ushort4* o = (ushort4*)((u16*)outp + (size_t)t * DMODEL);
    ushort4 q0, q1, q2;
#pragma unroll
    for (int e = 0; e < 4; ++e) {
      ((u16*)&q0)[e] = bf16r(y0[e]);
      ((u16*)&q1)[e] = bf16r(y1[e]);
      ((u16*)&q2)[e] = bf16r(y2[e]);
    }
    o[lane] = q0; o[lane + 64] = q1; o[lane + 128] = q2;
  } else {
    f32x4* o = (f32x4*)((float*)outp + (size_t)t * DMODEL);
    o[lane] = y0; o[lane + 64] = y1; o[lane + 128] = y2;
  }
}

// ------- bf16 MFMA NT GEMM (4-wave, TN<=128): 3-buffer, 2-ahead, counted vmcnt
// MODE 0: f32 = ; 1: f32 += ; 2: bf16 = gelu ; 3: bf16 =
template <int MODE, int TN>
__global__ __launch_bounds__(256) void gemm3(const u16* __restrict__ A,
                                             const u16* __restrict__ B,
                                             const float* __restrict__ bias,
                                             void* __restrict__ C,
                                             int M, int N, int K) {
  constexpr int NJ = TN / 32;
  constexpr int LPT = (TN == 128) ? 4 : 3;
  __shared__ u16 As[3][128 * 32];
  __shared__ u16 Bs[3][TN * 32];
  const int tid = threadIdx.x;
  const int w = tid >> 6, lane = tid & 63;

  const int nwg = gridDim.x * gridDim.y;
  int lin = blockIdx.y * gridDim.x + blockIdx.x;
  {
    int q = nwg >> 3, r = nwg & 7;
    int xcd = lin & 7, idx = lin >> 3;
    lin = (xcd < r ? xcd * (q + 1) : r * (q + 1) + (xcd - r) * q) + idx;
  }
  const int ntn = gridDim.y;
  const int m0 = (lin / ntn) * 128, n0 = (lin % ntn) * TN;

  const int wr = (w >> 1) * 64, wc = (w & 1) * (TN / 2);
  f32x4 acc[4][NJ] = {};

  const int srow = tid >> 2;
  const int scol = ((tid & 3) ^ ((srow >> 1) & 3)) * 8;
  int ar0 = m0 + srow;       if (ar0 >= M) ar0 = M - 1;
  int ar1 = m0 + 64 + srow;  if (ar1 >= M) ar1 = M - 1;
  const u16* Ag0 = A + (size_t)ar0 * K + scol;
  const u16* Ag1 = A + (size_t)ar1 * K + scol;
  const u16* Bg0 = B + (size_t)(n0 + srow) * K + scol;
  const u16* Bg1 = B + (size_t)(n0 + (TN == 128 ? 64 : 0) + srow) * K + scol;

  auto STAGE = [&](int buf, int kk) {
    gload16(Ag0 + kk, &As[buf][w * 512]);
    gload16(Ag1 + kk, &As[buf][2048 + w * 512]);
    gload16(Bg0 + kk, &Bs[buf][w * 512]);
    if (TN == 128) gload16(Bg1 + kk, &Bs[buf][2048 + w * 512]);
  };

  const int fr = lane & 15, lq = lane >> 4;
  const int kq = (lq ^ ((fr >> 1) & 3)) * 8;

  const int nt = K >> 5;
  STAGE(0, 0);
  STAGE(1, 32);
  asm volatile("s_waitcnt vmcnt(%0)" ::"n"(LPT) : "memory");
  __builtin_amdgcn_s_barrier();
  __builtin_amdgcn_sched_barrier(0);

  for (int t = 0; t < nt; ++t) {
    const int cur = t % 3;
    bf16x8 af[4], bfr[NJ];
#pragma unroll
    for (int i = 0; i < 4; ++i)
      af[i] = *(const bf16x8*)&As[cur][(wr + i * 16 + fr) * 32 + kq];
#pragma unroll
    for (int j = 0; j < NJ; ++j)
      bfr[j] = *(const bf16x8*)&Bs[cur][(wc + j * 16 + fr) * 32 + kq];
    const bool more = (t + 2 < nt);
    if (more) STAGE((t + 2) % 3, (t + 2) * 32);
#pragma unroll
    for (int i = 0; i < 4; ++i)
#pragma unroll
      for (int j = 0; j < NJ; ++j)
        acc[i][j] = __builtin_amdgcn_mfma_f32_16x16x32_bf16(af[i], bfr[j],
                                                            acc[i][j], 0, 0, 0);
    if (more)
      asm volatile("s_waitcnt vmcnt(%0)" ::"n"(LPT) : "memory");
    else
      asm volatile("s_waitcnt vmcnt(0)" ::: "memory");
    __builtin_amdgcn_s_barrier();
    __builtin_amdgcn_sched_barrier(0);
  }

  const int fq = lq * 4;
#pragma unroll
  for (int j = 0; j < NJ; ++j) {
    const int n = n0 + wc + j * 16 + fr;
    const float bb = bias[n];
#pragma unroll
    for (int i = 0; i < 4; ++i) {
      const int mbase = m0 + wr + i * 16 + fq;
#pragma unroll
      for (int r = 0; r < 4; ++r) {
        const int m = mbase + r;
        if (m < M) {
          const float v = acc[i][j][r] + bb;
          if (MODE == 0) ((float*)C)[(size_t)m * N + n] = v;
          else if (MODE == 1) ((float*)C)[(size_t)m * N + n] += v;
          else if (MODE == 2) ((u16*)C)[(size_t)m * N + n] = bf16r(gelu_f(v));
          else ((u16*)C)[(size_t)m * N + n] = bf16r(v);
        }
      }
    }
  }
}

// ------- gemm8: 8-wave 128x128 tile (wave tile 64x32) — higher occupancy -----
// Same 3-buffer / 2-ahead / counted-vmcnt schedule, same swizzle algebra.
// 512 threads stage the full 128-row A and B tiles in ONE gload each (LPT=2).
template <int MODE>
__global__ __launch_bounds__(512, 4) void gemm8(const u16* __restrict__ A,
                                                const u16* __restrict__ B,
                                                const float* __restrict__ bias,
                                                void* __restrict__ C,
                                                int M, int N, int K) {
  __shared__ u16 As[3][128 * 32];
  __shared__ u16 Bs[3][128 * 32];
  const int tid = threadIdx.x;
  const int w = tid >> 6, lane = tid & 63;

  const int nwg = gridDim.x * gridDim.y;
  int lin = blockIdx.y * gridDim.x + blockIdx.x;
  {
    int q = nwg >> 3, r = nwg & 7;
    int xcd = lin & 7, idx = lin >> 3;
    lin = (xcd < r ? xcd * (q + 1) : r * (q + 1) + (xcd - r) * q) + idx;
  }
  const int ntn = gridDim.y;
  const int m0 = (lin / ntn) * 128, n0 = (lin % ntn) * 128;

  const int wr = (w >> 2) * 64, wc = (w & 3) * 32;  // 2x4 wave grid, 64x32/wave
  f32x4 acc[4][2] = {};

  // staging: thread t -> row t/4 (0..127), chunk (t&3)^((row>>1)&3)
  const int srow = tid >> 2;
  const int scol = ((tid & 3) ^ ((srow >> 1) & 3)) * 8;
  int ar = m0 + srow;
  if (ar >= M) ar = M - 1;
  const u16* Ag = A + (size_t)ar * K + scol;
  const u16* Bg = B + (size_t)(n0 + srow) * K + scol;

  auto STAGE = [&](int buf, int kk) {
    gload16(Ag + kk, &As[buf][w * 512]);
    gload16(Bg + kk, &Bs[buf][w * 512]);
  };

  const int fr = lane & 15, lq = lane >> 4;
  const int kq = (lq ^ ((fr >> 1) & 3)) * 8;

  const int nt = K >> 5;
  STAGE(0, 0);
  STAGE(1, 32);
  asm volatile("s_waitcnt vmcnt(2)" ::: "memory");
  __builtin_amdgcn_s_barrier();
  __builtin_amdgcn_sched_barrier(0);

  for (int t = 0; t < nt; ++t) {
    const int cur = t % 3;
    bf16x8 af[4], bfr[2];
#pragma unroll
    for (int i = 0; i < 4; ++i)
      af[i] = *(const bf16x8*)&As[cur][(wr + i * 16 + fr) * 32 + kq];
#pragma unroll
    for (int j = 0; j < 2; ++j)
      bfr[j] = *(const bf16x8*)&Bs[cur][(wc + j * 16 + fr) * 32 + kq];
    const bool more = (t + 2 < nt);
    if (more) STAGE((t + 2) % 3, (t + 2) * 32);
#pragma unroll
    for (int i = 0; i < 4; ++i)
#pragma unroll
      for (int j = 0; j < 2; ++j)
        acc[i][j] = __builtin_amdgcn_mfma_f32_16x16x32_bf16(af[i], bfr[j],
                                                            acc[i][j], 0, 0, 0);
    if (more)
      asm volatile("s_waitcnt vmcnt(2)" ::: "memory");
    else
      asm volatile("s_waitcnt vmcnt(0)" ::: "memory");
    __builtin_amdgcn_s_barrier();
    __builtin_amdgcn_sched_barrier(0);
  }

  const int fq = lq * 4;
#pragma unroll
  for (int j = 0; j < 2; ++j) {
    const int n = n0 + wc + j * 16 + fr;
    const float bb = bias[n];
#pragma unroll
    for (int i = 0; i < 4; ++i) {
      const int mbase = m0 + wr + i * 16 + fq;
#pragma unroll
      for (int r = 0; r < 4; ++r) {
        const int m = mbase + r;
        if (m < M) {
          const float v = acc[i][j][r] + bb;
          if (MODE == 0) ((float*)C)[(size_t)m * N + n] = v;
          else if (MODE == 1) ((float*)C)[(size_t)m * N + n] += v;
          else if (MODE == 2) ((u16*)C)[(size_t)m * N + n] = bf16r(gelu_f(v));
          else ((u16*)C)[(size_t)m * N + n] = bf16r(v);
        }
      }
    }
  }
}

// ---------------- probe scores: one block per (b,h), bf16 qkv ----------------
__global__ __launch_bounds__(256) void probe_scores(const u16* __restrict__ qkv,
                                                    float* __restrict__ probs) {
  __shared__ float qrow[64];
  __shared__ float s[NTOK];
  __shared__ float red[4];
  const int bh = blockIdx.x;
  const int b = bh / HEADS, h = bh % HEADS;
  const int tid = threadIdx.x;
  const size_t row0 = (size_t)b * NTOK * QKVD;
  if (tid < 64) qrow[tid] = bf2f(qkv[row0 + h * HEADD + tid]);
  __syncthreads();
  const int sub = tid & 3;
  for (int k = tid >> 2; k < NTOK; k += 64) {
    const u16* kr = qkv + row0 + (size_t)k * QKVD + DMODEL + h * HEADD + sub * 16;
    bf16x8 k0 = *(const bf16x8*)kr;
    bf16x8 k1 = *(const bf16x8*)(kr + 8);
    float dot = 0.f;
#pragma unroll
    for (int e = 0; e < 8; ++e) {
      dot = fmaf(qrow[sub * 16 + e], bf2f((u16)k0[e]), dot);
      dot = fmaf(qrow[sub * 16 + 8 + e], bf2f((u16)k1[e]), dot);
    }
    dot += __shfl_xor(dot, 1);
    dot += __shfl_xor(dot, 2);
    if (sub == 0) s[k] = dot * 0.125f;
  }
  __syncthreads();
  float mx = -1e30f;
  for (int k = tid; k < NTOK; k += 256) mx = fmaxf(mx, s[k]);
  mx = blk_red_max(mx, red);
  float sm = 0.f;
  for (int k = tid; k < NTOK; k += 256) sm += expf(s[k] - mx);
  sm = blk_red_sum(sm, red);
  float inv = 1.f / sm;
  for (int k = tid; k < NTOK; k += 256)
    probs[(size_t)bh * NTOK + k] = expf(s[k] - mx) * inv;
}

// ---------------- top-k selection: one block per batch ----------------
__global__ __launch_bounds__(256) void topk_sel(const float* __restrict__ probs,
                                                const int* __restrict__ kpptr,
                                                int* __restrict__ topk) {
  __shared__ float accsc[NTOK];
  const int b = blockIdx.x, tid = threadIdx.x;
  for (int k = tid; k < NTOK; k += 256) {
    float a = 0.f;
#pragma unroll
    for (int h = 0; h < HEADS; ++h) a += probs[(size_t)(b * HEADS + h) * NTOK + k];
    accsc[k] = a;
  }
  __syncthreads();
  if (tid == 0) {
    int kpn = kpptr[0];
    if (kpn < 0) kpn = 0;
    if (kpn > 8) kpn = 8;
    for (int j = 0; j < kpn; ++j) {
      float best = -1e30f;
      int bi = 1;
      for (int k = 1; k < NTOK; ++k)
        if (accsc[k] > best) { best = accsc[k]; bi = k; }
      topk[b * 8 + j] = bi;
      accsc[bi] = -2e30f;
    }
    for (int j = kpn; j < 8; ++j) topk[b * 8 + j] = -1;
  }
}

// ---------------- MFMA attention, bf16 qkv input ----------------
__global__ __launch_bounds__(512, 1) void attn_mfma(
    const u16* __restrict__ qkv, const float* __restrict__ prompt_k,
    const float* __restrict__ prompt_v, const float* __restrict__ pk,
    const float* __restrict__ pv, const int* __restrict__ topk,
    const int* __restrict__ kpptr, u16* __restrict__ outp) {
  __shared__ u16 Ks[208 * 64];
  __shared__ u16 Vs[64 * 256];
  __shared__ u16 Ps[8][16 * 256];
  __shared__ float selb[NTOK];
  const int bh = blockIdx.x;
  const int b = bh / HEADS, h = bh % HEADS;
  const int tid = threadIdx.x, w = tid >> 6, lane = tid & 63;
  const int fr = lane & 15, lq = lane >> 4;

  int kpn = kpptr[0];
  if (kpn < 0) kpn = 0;
  if (kpn > 8) kpn = 8;
  for (int k = tid; k < NTOK; k += 512) {
    float sl = 0.f;
    for (int j = 0; j < kpn; ++j)
      if (topk[b * 8 + j] == k) sl = 1.f;
    selb[k] = sl;
  }
  __syncthreads();

  const size_t row0 = (size_t)b * NTOK * QKVD;
  const u16* kg = qkv + row0 + DMODEL + h * HEADD;
  const u16* vg = qkv + row0 + 2 * DMODEL + h * HEADD;
  for (int idx = tid; idx < 208 * 64; idx += 512) {
    int tok = idx >> 6, d = idx & 63;
    float v = 0.f;
    if (tok < NTOK) {
      v = bf2f(kg[(size_t)tok * QKVD + d]) + selb[tok] * pk[h * HEADD + d];
      if (tok == 0) v += prompt_k[h * HEADD + d];
    }
    int off = (tok * 128 + d * 2) ^ ((tok & 7) << 4);
    *(u16*)((char*)Ks + off) = bf16r(v);
  }
  for (int idx = tid; idx < 224 * 64; idx += 512) {
    int tok = idx >> 6, d = idx & 63;
    float v = 0.f;
    if (tok < NTOK) {
      v = bf2f(vg[(size_t)tok * QKVD + d]) + selb[tok] * pv[h * HEADD + d];
      if (tok == 0) v += prompt_v[h * HEADD + d];
    }
    int off = (d * 512 + tok * 2) ^ ((d & 7) << 4);
    *(u16*)((char*)Vs + off) = bf16r(v);
  }
  __syncthreads();

  u16* Pw = Ps[w];
  u16* ob = outp + (size_t)b * NTOK * DMODEL + h * HEADD;

#pragma unroll
  for (int pass = 0; pass < 2; ++pass) {
    const int qt = pass * 8 + w;
    const bool active = (qt < 14);
    if (active) {
      int qrow = qt * 16 + fr;
      if (qrow > NTOK - 1) qrow = NTOK - 1;
      const u16* qp = qkv + row0 + (size_t)qrow * QKVD + h * HEADD + lq * 8;
      bf16x8 aq0 = *(const bf16x8*)qp;
      bf16x8 aq1 = *(const bf16x8*)(qp + 32);
      f32x4 sa[13];
#pragma unroll
      for (int j = 0; j < 13; ++j) {
        int tok = j * 16 + fr;
        int o0 = (tok * 128 + lq * 16) ^ ((tok & 7) << 4);
        int o1 = (tok * 128 + 64 + lq * 16) ^ ((tok & 7) << 4);
        bf16x8 bk0 = *(const bf16x8*)((const char*)Ks + o0);
        bf16x8 bk1 = *(const bf16x8*)((const char*)Ks + o1);
        f32x4 z = {0.f, 0.f, 0.f, 0.f};
        z = __builtin_amdgcn_mfma_f32_16x16x32_bf16(aq0, bk0, z, 0, 0, 0);
        sa[j] = __builtin_amdgcn_mfma_f32_16x16x32_bf16(aq1, bk1, z, 0, 0, 0);
      }
      const bool v12 = (fr < 5);
      float m4[4] = {-1e30f, -1e30f, -1e30f, -1e30f};
#pragma unroll
      for (int j = 0; j < 13; ++j) {
        if (j == 12 && !v12) continue;
#pragma unroll
        for (int r = 0; r < 4; ++r) m4[r] = fmaxf(m4[r], sa[j][r] * 0.125f);
      }
#pragma unroll
      for (int o = 8; o; o >>= 1)
#pragma unroll
        for (int r = 0; r < 4; ++r) m4[r] = fmaxf(m4[r], __shfl_xor(m4[r], o));
      float s4[4] = {0.f, 0.f, 0.f, 0.f};
#pragma unroll
      for (int j = 0; j < 13; ++j) {
        const bool valid = (j < 12) || v12;
#pragma unroll
        for (int r = 0; r < 4; ++r) {
          float p = valid ? __expf(sa[j][r] * 0.125f - m4[r]) : 0.f;
          sa[j][r] = p;
          s4[r] += p;
        }
      }
#pragma unroll
      for (int o = 8; o; o >>= 1)
#pragma unroll
        for (int r = 0; r < 4; ++r) s4[r] += __shfl_xor(s4[r], o);
      float inv[4];
#pragma unroll
      for (int r = 0; r < 4; ++r) inv[r] = 1.f / s4[r];
#pragma unroll
      for (int r = 0; r < 4; ++r) {
        int row = lq * 4 + r;
        int rbase = row * 512, sw = (row & 7) << 4;
#pragma unroll
        for (int j = 0; j < 13; ++j) {
          int off = (rbase + (j * 16 + fr) * 2) ^ sw;
          *(u16*)((char*)Pw + off) = bf16r(sa[j][r] * inv[r]);
        }
        int offz = (rbase + (208 + fr) * 2) ^ sw;
        *(u16*)((char*)Pw + offz) = 0;
      }
    }
    __syncthreads();
    if (active) {
      f32x4 oa[4] = {};
#pragma unroll
      for (int kc = 0; kc < 7; ++kc) {
        int po = (fr * 512 + (kc * 32 + lq * 8) * 2) ^ ((fr & 7) << 4);
        bf16x8 pa = *(const bf16x8*)((const char*)Pw + po);
#pragma unroll
        for (int dt = 0; dt < 4; ++dt) {
          int d = dt * 16 + fr;
          int vo = (d * 512 + (kc * 32 + lq * 8) * 2) ^ ((d & 7) << 4);
          bf16x8 vb = *(const bf16x8*)((const char*)Vs + vo);
          oa[dt] = __builtin_amdgcn_mfma_f32_16x16x32_bf16(pa, vb, oa[dt], 0, 0, 0);
        }
      }
#pragma unroll
      for (int r = 0; r < 4; ++r) {
        int q = qt * 16 + lq * 4 + r;
        if (q < NTOK) {
          u16* orow = ob + (size_t)q * DMODEL;
#pragma unroll
          for (int dt = 0; dt < 4; ++dt) orow[dt * 16 + fr] = bf16r(oa[dt][r]);
        }
      }
    }
    __syncthreads();
  }
}

// ---------------- host ----------------
extern "C" void kernel_launch(void* const* d_in, const int* in_sizes, int n_in,
                              void* d_out, int out_size, void* d_ws, size_t ws_size,
                              hipStream_t stream) {
  const float* x = (const float*)d_in[0];
  const float* patch_w = (const float*)d_in[1];
  const float* patch_b = (const float*)d_in[2];
  const float* cls_tok = (const float*)d_in[3];
  const float* pos_emb = (const float*)d_in[4];
  const float* ln1_w = (const float*)d_in[5];
  const float* ln1_b = (const float*)d_in[6];
  const float* qkv_w = (const float*)d_in[7];
  const float* qkv_b = (const float*)d_in[8];
  const float* proj_w = (const float*)d_in[9];
  const float* proj_b = (const float*)d_in[10];
  const float* pk_par = (const float*)d_in[11];
  const float* pv_par = (const float*)d_in[12];
  const float* pr_k = (const float*)d_in[13];
  const float* pr_v = (const float*)d_in[14];
  const float* ln2_w = (const float*)d_in[15];
  const float* ln2_b = (const float*)d_in[16];
  const float* fc1_w = (const float*)d_in[17];
  const float* fc1_b = (const float*)d_in[18];
  const float* fc2_w = (const float*)d_in[19];
  const float* fc2_b = (const float*)d_in[20];
  const float* norm_w = (const float*)d_in[21];
  const float* norm_b = (const float*)d_in[22];
  const int* kp = (const int*)d_in[23];

  // workspace layout (bytes)
  char* base = (char*)d_ws;
  float* tokens = (float*)base;
  float* bufh = (float*)(base + 19365888ull);
  float* bufbig = (float*)(base + 38731776ull);
  u16* im2colb = (u16*)(base + 116195328ull);
  u16* patchwb = (u16*)(base + 125829120ull);
  int* topk = (int*)(base + 127008768ull);
  float* probs = (float*)(base + 127009792ull);
  u16* wbuf = (u16*)(base + 127312384ull);
  const size_t WBYTES = (size_t)WTOTAL * 2;
  const bool batch = ws_size >= 127312384ull + WBYTES * DEPTH;

  const int mt = (MTOK + 127) / 128;   // 50
  const int mtp = (MPAT + 127) / 128;  // 49
  const int lnb = (MTOK + 3) / 4;      // 1576

  if (batch)
    convert_all_w<<<dim3(WTOTAL / 1024, DEPTH), 256, 0, stream>>>(
        qkv_w, proj_w, fc1_w, fc2_w, wbuf);

  convert_bf16<<<(DMODEL * DMODEL / 4 + 255) / 256, 256, 0, stream>>>(
      patch_w, patchwb, DMODEL * DMODEL);
  im2col<<<(MPAT * DMODEL + 255) / 256, 256, 0, stream>>>(x, im2colb);
  gemm3<0, 64><<<dim3(mtp, DMODEL / 64), 256, 0, stream>>>(
      im2colb, patchwb, patch_b, bufh, MPAT, DMODEL, DMODEL);
  assemble<<<(MTOK * DMODEL + 255) / 256, 256, 0, stream>>>(bufh, cls_tok,
                                                            pos_emb, tokens);

  for (int l = 0; l < DEPTH; ++l) {
    u16* wl = batch ? (wbuf + (size_t)l * WTOTAL) : wbuf;
    if (!batch)
      convert_layer_w<<<(WTOTAL / 4 + 255) / 256, 256, 0, stream>>>(
          qkv_w + (size_t)l * QKVD * DMODEL,
          proj_w + (size_t)l * DMODEL * DMODEL,
          fc1_w + (size_t)l * MLPD * DMODEL,
          fc2_w + (size_t)l * DMODEL * MLPD, wl);
    layernorm_w<true><<<lnb, 256, 0, stream>>>(tokens, ln1_w + l * DMODEL,
                                               ln1_b + l * DMODEL, bufh, MTOK);
    gemm8<3><<<dim3(mt, QKVD / 128), 512, 0, stream>>>(
        (const u16*)bufh, wl + OFF_QKV, qkv_b + l * QKVD, bufbig,
        MTOK, QKVD, DMODEL);
    probe_scores<<<BATCH * HEADS, 256, 0, stream>>>((const u16*)bufbig, probs);
    topk_sel<<<BATCH, 256, 0, stream>>>(probs, kp, topk);
    attn_mfma<<<BATCH * HEADS, 512, 0, stream>>>(
        (const u16*)bufbig, pr_k + l * HEADS * HEADD, pr_v + l * HEADS * HEADD,
        pk_par + l * HEADS * HEADD, pv_par + l * HEADS * HEADD, topk, kp,
        (u16*)bufh);
    gemm3<1, 64><<<dim3(mt, DMODEL / 64), 256, 0, stream>>>(
        (const u16*)bufh, wl + OFF_PROJ, proj_b + l * DMODEL, tokens,
        MTOK, DMODEL, DMODEL);
    layernorm_w<true><<<lnb, 256, 0, stream>>>(tokens, ln2_w + l * DMODEL,
                                               ln2_b + l * DMODEL, bufh, MTOK);
    gemm8<2><<<dim3(mt, MLPD / 128), 512, 0, stream>>>(
        (const u16*)bufh, wl + OFF_FC1, fc1_b + l * MLPD, bufbig,
        MTOK, MLPD, DMODEL);
    gemm3<1, 64><<<dim3(mt, DMODEL / 64), 256, 0, stream>>>(
        (const u16*)bufbig, wl + OFF_FC2, fc2_b + l * DMODEL, tokens,
        MTOK, DMODEL, MLPD);
  }
  layernorm_w<false><<<lnb, 256, 0, stream>>>(tokens, norm_w, norm_b, d_out,
                                              MTOK);
}

// Round 15
// 3447.709 us; speedup vs baseline: 1.1303x; 1.0114x over previous
//
#include <hip/hip_runtime.h>
#include <math.h>

#define DMODEL 768
#define DEPTH 12
#define HEADS 12
#define HEADD 64
#define NTOK 197
#define BATCH 32
#define NPATCH 196
#define MTOK (BATCH * NTOK)    // 6304
#define MPAT (BATCH * NPATCH)  // 6272
#define QKVD 2304
#define MLPD 3072

typedef unsigned short u16;
typedef __attribute__((ext_vector_type(8))) short bf16x8;
typedef __attribute__((ext_vector_type(4))) float f32x4;

#define OFF_QKV 0
#define OFF_PROJ (QKVD * DMODEL)
#define OFF_FC1 (OFF_PROJ + DMODEL * DMODEL)
#define OFF_FC2 (OFF_FC1 + MLPD * DMODEL)
#define WTOTAL (OFF_FC2 + DMODEL * MLPD)   // 7077888 elements per layer

__device__ __forceinline__ u16 bf16r(float x) {
  union { float f; unsigned u; } c; c.f = x;
  unsigned u = c.u + 0x7FFF + ((c.u >> 16) & 1);
  return (u16)(u >> 16);
}
__device__ __forceinline__ float bf2f(u16 h) {
  union { unsigned u; float f; } c;
  c.u = (unsigned)h << 16;
  return c.f;
}
__device__ __forceinline__ float gelu_f(float x) {
  return 0.5f * x * (1.f + erff(x * 0.70710678118654752440f));
}
__device__ __forceinline__ void gload16(const void* g, void* l) {
  __builtin_amdgcn_global_load_lds(
      (const __attribute__((address_space(1))) void*)g,
      (__attribute__((address_space(3))) void*)l, 16, 0, 0);
}

// ---------------- block-wide reductions (256 threads) ----------------
__device__ __forceinline__ float blk_red_sum(float v, float* red) {
#pragma unroll
  for (int o = 32; o; o >>= 1) v += __shfl_xor(v, o);
  __syncthreads();
  if ((threadIdx.x & 63) == 0) red[threadIdx.x >> 6] = v;
  __syncthreads();
  return red[0] + red[1] + red[2] + red[3];
}
__device__ __forceinline__ float blk_red_max(float v, float* red) {
#pragma unroll
  for (int o = 32; o; o >>= 1) v = fmaxf(v, __shfl_xor(v, o));
  __syncthreads();
  if ((threadIdx.x & 63) == 0) red[threadIdx.x >> 6] = v;
  __syncthreads();
  return fmaxf(fmaxf(red[0], red[1]), fmaxf(red[2], red[3]));
}

// ---------------- f32 -> bf16 conversions ----------------
__global__ __launch_bounds__(256) void convert_bf16(const float* __restrict__ in,
                                                    u16* __restrict__ out, int n) {
  int i = (blockIdx.x * 256 + threadIdx.x) * 4;
  if (i >= n) return;
  float4 v = *(const float4*)(in + i);
  ushort4 o;
  o.x = bf16r(v.x); o.y = bf16r(v.y); o.z = bf16r(v.z); o.w = bf16r(v.w);
  *(ushort4*)(out + i) = o;
}

// one layer (fallback path)
__global__ __launch_bounds__(256) void convert_layer_w(
    const float* __restrict__ qkv_w, const float* __restrict__ proj_w,
    const float* __restrict__ fc1_w, const float* __restrict__ fc2_w,
    u16* __restrict__ wbuf) {
  int i = (blockIdx.x * 256 + threadIdx.x) * 4;
  if (i >= WTOTAL) return;
  const float* s;
  if (i < OFF_PROJ) s = qkv_w + i;
  else if (i < OFF_FC1) s = proj_w + (i - OFF_PROJ);
  else if (i < OFF_FC2) s = fc1_w + (i - OFF_FC1);
  else s = fc2_w + (i - OFF_FC2);
  float4 v = *(const float4*)s;
  ushort4 o;
  o.x = bf16r(v.x); o.y = bf16r(v.y); o.z = bf16r(v.z); o.w = bf16r(v.w);
  *(ushort4*)(wbuf + i) = o;
}

// all 12 layers in one dispatch. grid = (WTOTAL/1024, DEPTH)
__global__ __launch_bounds__(256) void convert_all_w(
    const float* __restrict__ qkv_w, const float* __restrict__ proj_w,
    const float* __restrict__ fc1_w, const float* __restrict__ fc2_w,
    u16* __restrict__ wall) {
  const int l = blockIdx.y;
  int i = (blockIdx.x * 256 + threadIdx.x) * 4;
  if (i >= WTOTAL) return;
  const float* s;
  if (i < OFF_PROJ) s = qkv_w + (size_t)l * QKVD * DMODEL + i;
  else if (i < OFF_FC1) s = proj_w + (size_t)l * DMODEL * DMODEL + (i - OFF_PROJ);
  else if (i < OFF_FC2) s = fc1_w + (size_t)l * MLPD * DMODEL + (i - OFF_FC1);
  else s = fc2_w + (size_t)l * DMODEL * MLPD + (i - OFF_FC2);
  float4 v = *(const float4*)s;
  ushort4 o;
  o.x = bf16r(v.x); o.y = bf16r(v.y); o.z = bf16r(v.z); o.w = bf16r(v.w);
  *(ushort4*)(wall + (size_t)l * WTOTAL + i) = o;
}

// ---------------- im2col (bf16 out) ----------------
__global__ __launch_bounds__(256) void im2col(const float* __restrict__ x,
                                              u16* __restrict__ col) {
  int idx = blockIdx.x * 256 + threadIdx.x;
  if (idx >= MPAT * DMODEL) return;
  int kk = idx % DMODEL;
  int m = idx / DMODEL;
  int bb = m / NPATCH, p = m % NPATCH;
  int ph = p / 14, pw = p % 14;
  int ch = kk >> 8, rem = kk & 255;
  int i = rem >> 4, j = rem & 15;
  col[idx] = bf16r(x[(((size_t)bb * 3 + ch) * 224 + ph * 16 + i) * 224 + pw * 16 + j]);
}

// ---------------- token assembly ----------------
__global__ __launch_bounds__(256) void assemble(const float* __restrict__ pat,
                                                const float* __restrict__ cls,
                                                const float* __restrict__ pos,
                                                float* __restrict__ tokens) {
  int idx = blockIdx.x * 256 + threadIdx.x;
  if (idx >= MTOK * DMODEL) return;
  int c = idx % DMODEL;
  int t = idx / DMODEL;
  int bb = t / NTOK, n = t % NTOK;
  float v;
  if (n == 0) v = cls[c];
  else v = pat[((size_t)bb * NPATCH + (n - 1)) * DMODEL + c];
  tokens[idx] = v + pos[n * DMODEL + c];
}

// ---------------- LayerNorm: one WAVE per token (4 tokens/block) ----------------
template <bool BF16OUT>
__global__ __launch_bounds__(256) void layernorm_w(const float* __restrict__ in,
                                                   const float* __restrict__ w,
                                                   const float* __restrict__ b,
                                                   void* __restrict__ outp,
                                                   int ntok) {
  const int wv = threadIdx.x >> 6, lane = threadIdx.x & 63;
  const int t = blockIdx.x * 4 + wv;
  if (t >= ntok) return;
  const f32x4* r = (const f32x4*)(in + (size_t)t * DMODEL);
  f32x4 x0 = r[lane], x1 = r[lane + 64], x2 = r[lane + 128];
  float s = (x0[0] + x0[1] + x0[2] + x0[3]) + (x1[0] + x1[1] + x1[2] + x1[3]) +
            (x2[0] + x2[1] + x2[2] + x2[3]);
#pragma unroll
  for (int o = 32; o; o >>= 1) s += __shfl_xor(s, o);
  const float mu = s * (1.f / 768.f);
  float vs = 0.f;
#pragma unroll
  for (int e = 0; e < 4; ++e) {
    float d0 = x0[e] - mu, d1 = x1[e] - mu, d2 = x2[e] - mu;
    vs += d0 * d0 + d1 * d1 + d2 * d2;
  }
#pragma unroll
  for (int o = 32; o; o >>= 1) vs += __shfl_xor(vs, o);
  const float is = rsqrtf(vs * (1.f / 768.f) + 1e-6f);
  const f32x4* wp = (const f32x4*)w;
  const f32x4* bp = (const f32x4*)b;
  f32x4 w0 = wp[lane], w1 = wp[lane + 64], w2 = wp[lane + 128];
  f32x4 b0 = bp[lane], b1 = bp[lane + 64], b2 = bp[lane + 128];
  f32x4 y0, y1, y2;
#pragma unroll
  for (int e = 0; e < 4; ++e) {
    y0[e] = (x0[e] - mu) * is * w0[e] + b0[e];
    y1[e] = (x1[e] - mu) * is * w1[e] + b1[e];
    y2[e] = (x2[e] - mu) * is * w2[e] + b2[e];
  }
  if (BF16OUT) {
    ushort4* o = (ushort4*)((u16*)outp + (size_t)t * DMODEL);
    ushort4 q0, q1, q2;
#pragma unroll
    for (int e = 0; e < 4; ++e) {
      ((u16*)&q0)[e] = bf16r(y0[e]);
      ((u16*)&q1)[e] = bf16r(y1[e]);
      ((u16*)&q2)[e] = bf16r(y2[e]);
    }
    o[lane] = q0; o[lane + 64] = q1; o[lane + 128] = q2;
  } else {
    f32x4* o = (f32x4*)((float*)outp + (size_t)t * DMODEL);
    o[lane] = y0; o[lane + 64] = y1; o[lane + 128] = y2;
  }
}

// ------- bf16 MFMA NT GEMM (4-wave, TN<=128): 3-buffer, 2-ahead, counted vmcnt
// Kept for patch-embed. MODE 0: f32 = ; 1: f32 += ; 2: bf16 gelu ; 3: bf16 =
template <int MODE, int TN>
__global__ __launch_bounds__(256) void gemm3(const u16* __restrict__ A,
                                             const u16* __restrict__ B,
                                             const float* __restrict__ bias,
                                             void* __restrict__ C,
                                             int M, int N, int K) {
  constexpr int NJ = TN / 32;
  constexpr int LPT = (TN == 128) ? 4 : 3;
  __shared__ u16 As[3][128 * 32];
  __shared__ u16 Bs[3][TN * 32];
  const int tid = threadIdx.x;
  const int w = tid >> 6, lane = tid & 63;

  const int nwg = gridDim.x * gridDim.y;
  int lin = blockIdx.y * gridDim.x + blockIdx.x;
  {
    int q = nwg >> 3, r = nwg & 7;
    int xcd = lin & 7, idx = lin >> 3;
    lin = (xcd < r ? xcd * (q + 1) : r * (q + 1) + (xcd - r) * q) + idx;
  }
  const int ntn = gridDim.y;
  const int m0 = (lin / ntn) * 128, n0 = (lin % ntn) * TN;

  const int wr = (w >> 1) * 64, wc = (w & 1) * (TN / 2);
  f32x4 acc[4][NJ] = {};

  const int srow = tid >> 2;
  const int scol = ((tid & 3) ^ ((srow >> 1) & 3)) * 8;
  int ar0 = m0 + srow;       if (ar0 >= M) ar0 = M - 1;
  int ar1 = m0 + 64 + srow;  if (ar1 >= M) ar1 = M - 1;
  const u16* Ag0 = A + (size_t)ar0 * K + scol;
  const u16* Ag1 = A + (size_t)ar1 * K + scol;
  const u16* Bg0 = B + (size_t)(n0 + srow) * K + scol;
  const u16* Bg1 = B + (size_t)(n0 + (TN == 128 ? 64 : 0) + srow) * K + scol;

  auto STAGE = [&](int buf, int kk) {
    gload16(Ag0 + kk, &As[buf][w * 512]);
    gload16(Ag1 + kk, &As[buf][2048 + w * 512]);
    gload16(Bg0 + kk, &Bs[buf][w * 512]);
    if (TN == 128) gload16(Bg1 + kk, &Bs[buf][2048 + w * 512]);
  };

  const int fr = lane & 15, lq = lane >> 4;
  const int kq = (lq ^ ((fr >> 1) & 3)) * 8;

  const int nt = K >> 5;
  STAGE(0, 0);
  STAGE(1, 32);
  asm volatile("s_waitcnt vmcnt(%0)" ::"n"(LPT) : "memory");
  __builtin_amdgcn_s_barrier();
  __builtin_amdgcn_sched_barrier(0);

  for (int t = 0; t < nt; ++t) {
    const int cur = t % 3;
    bf16x8 af[4], bfr[NJ];
#pragma unroll
    for (int i = 0; i < 4; ++i)
      af[i] = *(const bf16x8*)&As[cur][(wr + i * 16 + fr) * 32 + kq];
#pragma unroll
    for (int j = 0; j < NJ; ++j)
      bfr[j] = *(const bf16x8*)&Bs[cur][(wc + j * 16 + fr) * 32 + kq];
    const bool more = (t + 2 < nt);
    if (more) STAGE((t + 2) % 3, (t + 2) * 32);
#pragma unroll
    for (int i = 0; i < 4; ++i)
#pragma unroll
      for (int j = 0; j < NJ; ++j)
        acc[i][j] = __builtin_amdgcn_mfma_f32_16x16x32_bf16(af[i], bfr[j],
                                                            acc[i][j], 0, 0, 0);
    if (more)
      asm volatile("s_waitcnt vmcnt(%0)" ::"n"(LPT) : "memory");
    else
      asm volatile("s_waitcnt vmcnt(0)" ::: "memory");
    __builtin_amdgcn_s_barrier();
    __builtin_amdgcn_sched_barrier(0);
  }

  const int fq = lq * 4;
#pragma unroll
  for (int j = 0; j < NJ; ++j) {
    const int n = n0 + wc + j * 16 + fr;
    const float bb = bias[n];
#pragma unroll
    for (int i = 0; i < 4; ++i) {
      const int mbase = m0 + wr + i * 16 + fq;
#pragma unroll
      for (int r = 0; r < 4; ++r) {
        const int m = mbase + r;
        if (m < M) {
          const float v = acc[i][j][r] + bb;
          if (MODE == 0) ((float*)C)[(size_t)m * N + n] = v;
          else if (MODE == 1) ((float*)C)[(size_t)m * N + n] += v;
          else if (MODE == 2) ((u16*)C)[(size_t)m * N + n] = bf16r(gelu_f(v));
          else ((u16*)C)[(size_t)m * N + n] = bf16r(v);
        }
      }
    }
  }
}

// ------- gemm8: 8-wave 128xTN tile — register-light, high occupancy ---------
// TN=128: wave tile 64x32 (2x4 grid). TN=64: wave tile 32x32 (4x2 grid),
// LDS 36KB -> 4 blocks/CU = 32 waves/CU. For TN=64 only waves 0-3 stage B
// (wave-uniform branch; per-wave vmcnt constants differ accordingly).
template <int MODE, int TN>
__global__ __launch_bounds__(512, 4) void gemm8(const u16* __restrict__ A,
                                                const u16* __restrict__ B,
                                                const float* __restrict__ bias,
                                                void* __restrict__ C,
                                                int M, int N, int K) {
  constexpr int NI = (TN == 128) ? 4 : 2;
  __shared__ u16 As[3][128 * 32];
  __shared__ u16 Bs[3][TN * 32];
  const int tid = threadIdx.x;
  const int w = tid >> 6, lane = tid & 63;

  const int nwg = gridDim.x * gridDim.y;
  int lin = blockIdx.y * gridDim.x + blockIdx.x;
  {
    int q = nwg >> 3, r = nwg & 7;
    int xcd = lin & 7, idx = lin >> 3;
    lin = (xcd < r ? xcd * (q + 1) : r * (q + 1) + (xcd - r) * q) + idx;
  }
  const int ntn = gridDim.y;
  const int m0 = (lin / ntn) * 128, n0 = (lin % ntn) * TN;

  const int wr = (TN == 128) ? (w >> 2) * 64 : (w >> 1) * 32;
  const int wc = (TN == 128) ? (w & 3) * 32 : (w & 1) * 32;
  f32x4 acc[NI][2] = {};

  // staging: thread t -> A row t/4 (0..127), chunk (t&3)^((row>>1)&3)
  const int srow = tid >> 2;
  const int scol = ((tid & 3) ^ ((srow >> 1) & 3)) * 8;
  int ar = m0 + srow;
  if (ar >= M) ar = M - 1;
  const u16* Ag = A + (size_t)ar * K + scol;
  const u16* Bg = B + (size_t)(n0 + srow) * K + scol;  // srow<64 when used (TN=64)
  const bool doB = (TN == 128) || (w < 4);

  auto STAGE = [&](int buf, int kk) {
    gload16(Ag + kk, &As[buf][w * 512]);
    if (doB) gload16(Bg + kk, &Bs[buf][w * 512]);
  };

  const int fr = lane & 15, lq = lane >> 4;
  const int kq = (lq ^ ((fr >> 1) & 3)) * 8;

  const int nt = K >> 5;
  STAGE(0, 0);
  STAGE(1, 32);
  if (doB)
    asm volatile("s_waitcnt vmcnt(2)" ::: "memory");
  else
    asm volatile("s_waitcnt vmcnt(1)" ::: "memory");
  __builtin_amdgcn_s_barrier();
  __builtin_amdgcn_sched_barrier(0);

  for (int t = 0; t < nt; ++t) {
    const int cur = t % 3;
    bf16x8 af[NI], bfr[2];
#pragma unroll
    for (int i = 0; i < NI; ++i)
      af[i] = *(const bf16x8*)&As[cur][(wr + i * 16 + fr) * 32 + kq];
#pragma unroll
    for (int j = 0; j < 2; ++j)
      bfr[j] = *(const bf16x8*)&Bs[cur][(wc + j * 16 + fr) * 32 + kq];
    const bool more = (t + 2 < nt);
    if (more) STAGE((t + 2) % 3, (t + 2) * 32);
#pragma unroll
    for (int i = 0; i < NI; ++i)
#pragma unroll
      for (int j = 0; j < 2; ++j)
        acc[i][j] = __builtin_amdgcn_mfma_f32_16x16x32_bf16(af[i], bfr[j],
                                                            acc[i][j], 0, 0, 0);
    if (more) {
      if (doB)
        asm volatile("s_waitcnt vmcnt(2)" ::: "memory");
      else
        asm volatile("s_waitcnt vmcnt(1)" ::: "memory");
    } else {
      asm volatile("s_waitcnt vmcnt(0)" ::: "memory");
    }
    __builtin_amdgcn_s_barrier();
    __builtin_amdgcn_sched_barrier(0);
  }

  const int fq = lq * 4;
#pragma unroll
  for (int j = 0; j < 2; ++j) {
    const int n = n0 + wc + j * 16 + fr;
    const float bb = bias[n];
#pragma unroll
    for (int i = 0; i < NI; ++i) {
      const int mbase = m0 + wr + i * 16 + fq;
#pragma unroll
      for (int r = 0; r < 4; ++r) {
        const int m = mbase + r;
        if (m < M) {
          const float v = acc[i][j][r] + bb;
          if (MODE == 0) ((float*)C)[(size_t)m * N + n] = v;
          else if (MODE == 1) ((float*)C)[(size_t)m * N + n] += v;
          else if (MODE == 2) ((u16*)C)[(size_t)m * N + n] = bf16r(gelu_f(v));
          else ((u16*)C)[(size_t)m * N + n] = bf16r(v);
        }
      }
    }
  }
}

// ---------------- probe scores: one block per (b,h), bf16 qkv ----------------
__global__ __launch_bounds__(256) void probe_scores(const u16* __restrict__ qkv,
                                                    float* __restrict__ probs) {
  __shared__ float qrow[64];
  __shared__ float s[NTOK];
  __shared__ float red[4];
  const int bh = blockIdx.x;
  const int b = bh / HEADS, h = bh % HEADS;
  const int tid = threadIdx.x;
  const size_t row0 = (size_t)b * NTOK * QKVD;
  if (tid < 64) qrow[tid] = bf2f(qkv[row0 + h * HEADD + tid]);
  __syncthreads();
  const int sub = tid & 3;
  for (int k = tid >> 2; k < NTOK; k += 64) {
    const u16* kr = qkv + row0 + (size_t)k * QKVD + DMODEL + h * HEADD + sub * 16;
    bf16x8 k0 = *(const bf16x8*)kr;
    bf16x8 k1 = *(const bf16x8*)(kr + 8);
    float dot = 0.f;
#pragma unroll
    for (int e = 0; e < 8; ++e) {
      dot = fmaf(qrow[sub * 16 + e], bf2f((u16)k0[e]), dot);
      dot = fmaf(qrow[sub * 16 + 8 + e], bf2f((u16)k1[e]), dot);
    }
    dot += __shfl_xor(dot, 1);
    dot += __shfl_xor(dot, 2);
    if (sub == 0) s[k] = dot * 0.125f;
  }
  __syncthreads();
  float mx = -1e30f;
  for (int k = tid; k < NTOK; k += 256) mx = fmaxf(mx, s[k]);
  mx = blk_red_max(mx, red);
  float sm = 0.f;
  for (int k = tid; k < NTOK; k += 256) sm += expf(s[k] - mx);
  sm = blk_red_sum(sm, red);
  float inv = 1.f / sm;
  for (int k = tid; k < NTOK; k += 256)
    probs[(size_t)bh * NTOK + k] = expf(s[k] - mx) * inv;
}

// ---------------- top-k selection: one block per batch ----------------
__global__ __launch_bounds__(256) void topk_sel(const float* __restrict__ probs,
                                                const int* __restrict__ kpptr,
                                                int* __restrict__ topk) {
  __shared__ float accsc[NTOK];
  const int b = blockIdx.x, tid = threadIdx.x;
  for (int k = tid; k < NTOK; k += 256) {
    float a = 0.f;
#pragma unroll
    for (int h = 0; h < HEADS; ++h) a += probs[(size_t)(b * HEADS + h) * NTOK + k];
    accsc[k] = a;
  }
  __syncthreads();
  if (tid == 0) {
    int kpn = kpptr[0];
    if (kpn < 0) kpn = 0;
    if (kpn > 8) kpn = 8;
    for (int j = 0; j < kpn; ++j) {
      float best = -1e30f;
      int bi = 1;
      for (int k = 1; k < NTOK; ++k)
        if (accsc[k] > best) { best = accsc[k]; bi = k; }
      topk[b * 8 + j] = bi;
      accsc[bi] = -2e30f;
    }
    for (int j = kpn; j < 8; ++j) topk[b * 8 + j] = -1;
  }
}

// ---------------- MFMA attention, bf16 qkv input ----------------
__global__ __launch_bounds__(512, 1) void attn_mfma(
    const u16* __restrict__ qkv, const float* __restrict__ prompt_k,
    const float* __restrict__ prompt_v, const float* __restrict__ pk,
    const float* __restrict__ pv, const int* __restrict__ topk,
    const int* __restrict__ kpptr, u16* __restrict__ outp) {
  __shared__ u16 Ks[208 * 64];
  __shared__ u16 Vs[64 * 256];
  __shared__ u16 Ps[8][16 * 256];
  __shared__ float selb[NTOK];
  const int bh = blockIdx.x;
  const int b = bh / HEADS, h = bh % HEADS;
  const int tid = threadIdx.x, w = tid >> 6, lane = tid & 63;
  const int fr = lane & 15, lq = lane >> 4;

  int kpn = kpptr[0];
  if (kpn < 0) kpn = 0;
  if (kpn > 8) kpn = 8;
  for (int k = tid; k < NTOK; k += 512) {
    float sl = 0.f;
    for (int j = 0; j < kpn; ++j)
      if (topk[b * 8 + j] == k) sl = 1.f;
    selb[k] = sl;
  }
  __syncthreads();

  const size_t row0 = (size_t)b * NTOK * QKVD;
  const u16* kg = qkv + row0 + DMODEL + h * HEADD;
  const u16* vg = qkv + row0 + 2 * DMODEL + h * HEADD;
  for (int idx = tid; idx < 208 * 64; idx += 512) {
    int tok = idx >> 6, d = idx & 63;
    float v = 0.f;
    if (tok < NTOK) {
      v = bf2f(kg[(size_t)tok * QKVD + d]) + selb[tok] * pk[h * HEADD + d];
      if (tok == 0) v += prompt_k[h * HEADD + d];
    }
    int off = (tok * 128 + d * 2) ^ ((tok & 7) << 4);
    *(u16*)((char*)Ks + off) = bf16r(v);
  }
  for (int idx = tid; idx < 224 * 64; idx += 512) {
    int tok = idx >> 6, d = idx & 63;
    float v = 0.f;
    if (tok < NTOK) {
      v = bf2f(vg[(size_t)tok * QKVD + d]) + selb[tok] * pv[h * HEADD + d];
      if (tok == 0) v += prompt_v[h * HEADD + d];
    }
    int off = (d * 512 + tok * 2) ^ ((d & 7) << 4);
    *(u16*)((char*)Vs + off) = bf16r(v);
  }
  __syncthreads();

  u16* Pw = Ps[w];
  u16* ob = outp + (size_t)b * NTOK * DMODEL + h * HEADD;

#pragma unroll
  for (int pass = 0; pass < 2; ++pass) {
    const int qt = pass * 8 + w;
    const bool active = (qt < 14);
    if (active) {
      int qrow = qt * 16 + fr;
      if (qrow > NTOK - 1) qrow = NTOK - 1;
      const u16* qp = qkv + row0 + (size_t)qrow * QKVD + h * HEADD + lq * 8;
      bf16x8 aq0 = *(const bf16x8*)qp;
      bf16x8 aq1 = *(const bf16x8*)(qp + 32);
      f32x4 sa[13];
#pragma unroll
      for (int j = 0; j < 13; ++j) {
        int tok = j * 16 + fr;
        int o0 = (tok * 128 + lq * 16) ^ ((tok & 7) << 4);
        int o1 = (tok * 128 + 64 + lq * 16) ^ ((tok & 7) << 4);
        bf16x8 bk0 = *(const bf16x8*)((const char*)Ks + o0);
        bf16x8 bk1 = *(const bf16x8*)((const char*)Ks + o1);
        f32x4 z = {0.f, 0.f, 0.f, 0.f};
        z = __builtin_amdgcn_mfma_f32_16x16x32_bf16(aq0, bk0, z, 0, 0, 0);
        sa[j] = __builtin_amdgcn_mfma_f32_16x16x32_bf16(aq1, bk1, z, 0, 0, 0);
      }
      const bool v12 = (fr < 5);
      float m4[4] = {-1e30f, -1e30f, -1e30f, -1e30f};
#pragma unroll
      for (int j = 0; j < 13; ++j) {
        if (j == 12 && !v12) continue;
#pragma unroll
        for (int r = 0; r < 4; ++r) m4[r] = fmaxf(m4[r], sa[j][r] * 0.125f);
      }
#pragma unroll
      for (int o = 8; o; o >>= 1)
#pragma unroll
        for (int r = 0; r < 4; ++r) m4[r] = fmaxf(m4[r], __shfl_xor(m4[r], o));
      float s4[4] = {0.f, 0.f, 0.f, 0.f};
#pragma unroll
      for (int j = 0; j < 13; ++j) {
        const bool valid = (j < 12) || v12;
#pragma unroll
        for (int r = 0; r < 4; ++r) {
          float p = valid ? __expf(sa[j][r] * 0.125f - m4[r]) : 0.f;
          sa[j][r] = p;
          s4[r] += p;
        }
      }
#pragma unroll
      for (int o = 8; o; o >>= 1)
#pragma unroll
        for (int r = 0; r < 4; ++r) s4[r] += __shfl_xor(s4[r], o);
      float inv[4];
#pragma unroll
      for (int r = 0; r < 4; ++r) inv[r] = 1.f / s4[r];
#pragma unroll
      for (int r = 0; r < 4; ++r) {
        int row = lq * 4 + r;
        int rbase = row * 512, sw = (row & 7) << 4;
#pragma unroll
        for (int j = 0; j < 13; ++j) {
          int off = (rbase + (j * 16 + fr) * 2) ^ sw;
          *(u16*)((char*)Pw + off) = bf16r(sa[j][r] * inv[r]);
        }
        int offz = (rbase + (208 + fr) * 2) ^ sw;
        *(u16*)((char*)Pw + offz) = 0;
      }
    }
    __syncthreads();
    if (active) {
      f32x4 oa[4] = {};
#pragma unroll
      for (int kc = 0; kc < 7; ++kc) {
        int po = (fr * 512 + (kc * 32 + lq * 8) * 2) ^ ((fr & 7) << 4);
        bf16x8 pa = *(const bf16x8*)((const char*)Pw + po);
#pragma unroll
        for (int dt = 0; dt < 4; ++dt) {
          int d = dt * 16 + fr;
          int vo = (d * 512 + (kc * 32 + lq * 8) * 2) ^ ((d & 7) << 4);
          bf16x8 vb = *(const bf16x8*)((const char*)Vs + vo);
          oa[dt] = __builtin_amdgcn_mfma_f32_16x16x32_bf16(pa, vb, oa[dt], 0, 0, 0);
        }
      }
#pragma unroll
      for (int r = 0; r < 4; ++r) {
        int q = qt * 16 + lq * 4 + r;
        if (q < NTOK) {
          u16* orow = ob + (size_t)q * DMODEL;
#pragma unroll
          for (int dt = 0; dt < 4; ++dt) orow[dt * 16 + fr] = bf16r(oa[dt][r]);
        }
      }
    }
    __syncthreads();
  }
}

// ---------------- host ----------------
extern "C" void kernel_launch(void* const* d_in, const int* in_sizes, int n_in,
                              void* d_out, int out_size, void* d_ws, size_t ws_size,
                              hipStream_t stream) {
  const float* x = (const float*)d_in[0];
  const float* patch_w = (const float*)d_in[1];
  const float* patch_b = (const float*)d_in[2];
  const float* cls_tok = (const float*)d_in[3];
  const float* pos_emb = (const float*)d_in[4];
  const float* ln1_w = (const float*)d_in[5];
  const float* ln1_b = (const float*)d_in[6];
  const float* qkv_w = (const float*)d_in[7];
  const float* qkv_b = (const float*)d_in[8];
  const float* proj_w = (const float*)d_in[9];
  const float* proj_b = (const float*)d_in[10];
  const float* pk_par = (const float*)d_in[11];
  const float* pv_par = (const float*)d_in[12];
  const float* pr_k = (const float*)d_in[13];
  const float* pr_v = (const float*)d_in[14];
  const float* ln2_w = (const float*)d_in[15];
  const float* ln2_b = (const float*)d_in[16];
  const float* fc1_w = (const float*)d_in[17];
  const float* fc1_b = (const float*)d_in[18];
  const float* fc2_w = (const float*)d_in[19];
  const float* fc2_b = (const float*)d_in[20];
  const float* norm_w = (const float*)d_in[21];
  const float* norm_b = (const float*)d_in[22];
  const int* kp = (const int*)d_in[23];

  // workspace layout (bytes)
  char* base = (char*)d_ws;
  float* tokens = (float*)base;
  float* bufh = (float*)(base + 19365888ull);
  float* bufbig = (float*)(base + 38731776ull);
  u16* im2colb = (u16*)(base + 116195328ull);
  u16* patchwb = (u16*)(base + 125829120ull);
  int* topk = (int*)(base + 127008768ull);
  float* probs = (float*)(base + 127009792ull);
  u16* wbuf = (u16*)(base + 127312384ull);
  const size_t WBYTES = (size_t)WTOTAL * 2;
  const bool batch = ws_size >= 127312384ull + WBYTES * DEPTH;

  const int mt = (MTOK + 127) / 128;   // 50
  const int mtp = (MPAT + 127) / 128;  // 49
  const int lnb = (MTOK + 3) / 4;      // 1576

  if (batch)
    convert_all_w<<<dim3(WTOTAL / 1024, DEPTH), 256, 0, stream>>>(
        qkv_w, proj_w, fc1_w, fc2_w, wbuf);

  convert_bf16<<<(DMODEL * DMODEL / 4 + 255) / 256, 256, 0, stream>>>(
      patch_w, patchwb, DMODEL * DMODEL);
  im2col<<<(MPAT * DMODEL + 255) / 256, 256, 0, stream>>>(x, im2colb);
  gemm3<0, 64><<<dim3(mtp, DMODEL / 64), 256, 0, stream>>>(
      im2colb, patchwb, patch_b, bufh, MPAT, DMODEL, DMODEL);
  assemble<<<(MTOK * DMODEL + 255) / 256, 256, 0, stream>>>(bufh, cls_tok,
                                                            pos_emb, tokens);

  for (int l = 0; l < DEPTH; ++l) {
    u16* wl = batch ? (wbuf + (size_t)l * WTOTAL) : wbuf;
    if (!batch)
      convert_layer_w<<<(WTOTAL / 4 + 255) / 256, 256, 0, stream>>>(
          qkv_w + (size_t)l * QKVD * DMODEL,
          proj_w + (size_t)l * DMODEL * DMODEL,
          fc1_w + (size_t)l * MLPD * DMODEL,
          fc2_w + (size_t)l * DMODEL * MLPD, wl);
    layernorm_w<true><<<lnb, 256, 0, stream>>>(tokens, ln1_w + l * DMODEL,
                                               ln1_b + l * DMODEL, bufh, MTOK);
    gemm8<3, 128><<<dim3(mt, QKVD / 128), 512, 0, stream>>>(
        (const u16*)bufh, wl + OFF_QKV, qkv_b + l * QKVD, bufbig,
        MTOK, QKVD, DMODEL);
    probe_scores<<<BATCH * HEADS, 256, 0, stream>>>((const u16*)bufbig, probs);
    topk_sel<<<BATCH, 256, 0, stream>>>(probs, kp, topk);
    attn_mfma<<<BATCH * HEADS, 512, 0, stream>>>(
        (const u16*)bufbig, pr_k + l * HEADS * HEADD, pr_v + l * HEADS * HEADD,
        pk_par + l * HEADS * HEADD, pv_par + l * HEADS * HEADD, topk, kp,
        (u16*)bufh);
    gemm8<1, 64><<<dim3(mt, DMODEL / 64), 512, 0, stream>>>(
        (const u16*)bufh, wl + OFF_PROJ, proj_b + l * DMODEL, tokens,
        MTOK, DMODEL, DMODEL);
    layernorm_w<true><<<lnb, 256, 0, stream>>>(tokens, ln2_w + l * DMODEL,
                                               ln2_b + l * DMODEL, bufh, MTOK);
    gemm8<2, 128><<<dim3(mt, MLPD / 128), 512, 0, stream>>>(
        (const u16*)bufh, wl + OFF_FC1, fc1_b + l * MLPD, bufbig,
        MTOK, MLPD, DMODEL);
    gemm8<1, 64><<<dim3(mt, DMODEL / 64), 512, 0, stream>>>(
        (const u16*)bufbig, wl + OFF_FC2, fc2_b + l * DMODEL, tokens,
        MTOK, DMODEL, MLPD);
  }
  layernorm_w<false><<<lnb, 256, 0, stream>>>(tokens, norm_w, norm_b, d_out,
                                              MTOK);
}